// Round 8
// baseline (650.629 us; speedup 1.0000x reference)
//
#include <hip/hip_runtime.h>
#include <hip/hip_bf16.h>

#define EPSF 1e-20f
typedef __hip_bfloat16 bf16;
typedef unsigned int u32;

__device__ __forceinline__ float rcpf_(float v) { return __builtin_amdgcn_rcpf(v); }
__device__ __forceinline__ float bits2f(u32 b) { union { u32 i; float f; } u; u.i = b; return u.f; }
__device__ __forceinline__ float lo2f(u32 v) { return bits2f(v << 16); }
__device__ __forceinline__ float hi2f(u32 v) { return bits2f(v & 0xffff0000u); }
__device__ __forceinline__ u32 f2us(float f) {
    bf16 h = __float2bfloat16(f);
    unsigned short s;
    __builtin_memcpy(&s, &h, 2);
    return (u32)s;
}
// pixel pack: (x0,c0,x1,c1) as 4x bf16 in a uint2
__device__ __forceinline__ uint2 packpx(float x0, float c0, float x1, float c1) {
    return make_uint2(f2us(x0) | (f2us(c0) << 16), f2us(x1) | (f2us(c1) << 16));
}
// unpack to (p0,c0,p1,c1) with p = x*c
__device__ __forceinline__ float4 unpk(uint2 v) {
    float x0 = lo2f(v.x), c0 = hi2f(v.x), x1 = lo2f(v.y), c1 = hi2f(v.y);
    return make_float4(x0 * c0, c0, x1 * c1, c1);
}

// ---- problem dims (fixed by setup_inputs) ----
#define B_ 16
#define H1 352
#define W1 1216
#define H2 176
#define W2 608
#define H3 88
#define W3 304
#define H4 44
#define W4 152

// ---------------------------------------------------------------------------
// Weight prep: w = softplus(10*p)/10, per-out-ch kernel sums + inverse sums.
// wb floats: wt1@0(50) s1@64 | wt2@96(100) s2@224 | wt3@256(100) s3@384 |
// wt4@416(72) s4@512 | wt5@544(72) s5@640 | wt6@672(72) s6@768 |
// wt7@800(2) s7@804 | is1@808 is2@810 is3@812 is4@814 is5@816 is6@818 is7@820
// ---------------------------------------------------------------------------
__global__ void prep_weights(const float* w1, const float* w2, const float* w3,
                             const float* w4, const float* w5, const float* w6,
                             const float* w7, float* wb) {
    const float* ptrs[7] = {w1, w2, w3, w4, w5, w6, w7};
    const int ns[7]   = {50, 100, 100, 72, 72, 72, 2};
    const int offs[7] = {0, 96, 256, 416, 544, 672, 800};
    for (int it = 0; it < 7; ++it)
        for (int i = threadIdx.x; i < ns[it]; i += blockDim.x) {
            float z = 10.f * ptrs[it][i];
            float sp = (z > 20.f) ? z : log1pf(expf(z));
            wb[offs[it] + i] = sp * 0.1f;
        }
    __syncthreads();
    if (threadIdx.x < 13) {
        const int t = threadIdx.x;
        const int it = (t == 12) ? 6 : (t >> 1);
        const int o  = (t == 12) ? 0 : (t & 1);
        const int offs2[7] = {0, 96, 256, 416, 544, 672, 800};
        const int klen2[7] = {25, 50, 50, 36, 36, 36, 2};
        const int soff2[7] = {64, 224, 384, 512, 640, 768, 804};
        float s = 0.f;
        for (int i = 0; i < klen2[it]; ++i) s += wb[offs2[it] + o * klen2[it] + i];
        wb[soff2[it] + o] = s;
        wb[808 + t] = 1.f / s;     // t=0..11 -> 808..819 (is1..is6), t=12 -> 820 (is7)
    }
}

// ---------------------------------------------------------------------------
// Fused L1 encoder + pool, v6: 32-wide x 16-tall tile.
// LDS: A1 2*24*21 f4 = 16.1KB + U4 2*20*19 f4 = 12.2KB (stage0 10.3KB union)
//   = 28.3KB -> 5 blocks/CU -> 20 waves/CU (was 49KB -> 3 blocks -> 12).
// Stage quad counts 240/180/128 < 256 -> every stage single-pass (no
// imbalance). Halo FMA +18% traded for +67% latency hiding.
// ---------------------------------------------------------------------------
#define TW 32
#define TH 16

__global__ __launch_bounds__(256) void fused_l1pool(
    const float* __restrict__ x0g, const float* __restrict__ c0g,
    const float* __restrict__ wb,
    const float* __restrict__ b1, const float* __restrict__ b2, const float* __restrict__ b3,
    uint2* __restrict__ Apk, uint2* __restrict__ P1pk) {

    __shared__ float4 A1buf[2 * 24 * 21];   // stage1 out halves (stride 21). 16128 B
    __shared__ float4 U4buf[2 * 20 * 19];   // stage0 (float2 view) / stage2 out. 12160 B
    float4* A1e = A1buf;            float4* A1o = A1buf + 24 * 21;
    float4* U4e = U4buf;            float4* U4o = U4buf + 20 * 19;
    float2* U2e = (float2*)U4buf;   float2* U2o = U2e + 28 * 23;   // 1288 f2 = 10304B <= 12160

    const int tid = threadIdx.x;
    const int base_h = blockIdx.y * TH;
    const int base_w = blockIdx.x * TW;
    const int b = blockIdx.z;
    const float* xp = x0g + (long)b * (H1 * W1);
    const float* cpg = c0g + (long)b * (H1 * W1);

    // stage 0: 28x44 (p,c) tile at origin (-6,-6); column-pair float2 loads.
    // 28 rows x 22 pairs = 616 items.
    for (int i = tid; i < 28 * 22; i += 256) {
        int r = i / 22, cp2 = i % 22;
        int gh = base_h - 6 + r, gw = base_w - 6 + 2 * cp2;
        float2 xv = make_float2(0.f, 0.f), cv = make_float2(0.f, 0.f);
        if (gh >= 0 && gh < H1 && gw >= 0 && gw < W1) {
            long o = (long)gh * W1 + gw;
            xv = *reinterpret_cast<const float2*>(xp + o);
            cv = *reinterpret_cast<const float2*>(cpg + o);
        }
        U2e[r * 23 + cp2] = make_float2(xv.x * cv.x, cv.x);
        U2o[r * 23 + cp2] = make_float2(xv.y * cv.y, cv.y);
    }
    __syncthreads();

    // stage 1: conv1 (CIN=1), 24x40 outputs (origin -4), 12x20=240 quads.
    if (tid < 240) {
        const float is0 = wb[808], is1 = wb[809];
        const float bb0 = b1[0], bb1 = b1[1];
        int qr = tid / 20, qc = tid % 20;
        int r0 = 2 * qr;
        float acc[2][2][4];
        #pragma unroll
        for (int a = 0; a < 2; ++a)
            #pragma unroll
            for (int o = 0; o < 2; ++o)
                #pragma unroll
                for (int k = 0; k < 4; ++k) acc[a][o][k] = 0.f;
        #pragma unroll
        for (int tr = 0; tr < 6; ++tr) {
            const int rr = (r0 + tr) * 23;
            float2 t[6];
            t[0] = U2e[rr + qc];     t[1] = U2o[rr + qc];
            t[2] = U2e[rr + qc + 1]; t[3] = U2o[rr + qc + 1];
            t[4] = U2e[rr + qc + 2]; t[5] = U2o[rr + qc + 2];
            #pragma unroll
            for (int orr = 0; orr < 2; ++orr) {
                const int dh = tr - orr;
                if (dh < 0 || dh > 4) continue;
                #pragma unroll
                for (int dw = 0; dw < 5; ++dw) {
                    float wA = wb[dh * 5 + dw];
                    float wB = wb[25 + dh * 5 + dw];
                    #pragma unroll
                    for (int oc = 0; oc < 2; ++oc) {
                        float2 v = t[dw + oc];
                        acc[orr][oc][0] = fmaf(wA, v.x, acc[orr][oc][0]);
                        acc[orr][oc][1] = fmaf(wA, v.y, acc[orr][oc][1]);
                        acc[orr][oc][2] = fmaf(wB, v.x, acc[orr][oc][2]);
                        acc[orr][oc][3] = fmaf(wB, v.y, acc[orr][oc][3]);
                    }
                }
            }
        }
        #pragma unroll
        for (int orr = 0; orr < 2; ++orr) {
            int r = r0 + orr;
            int gh = base_h - 4 + r;
            #pragma unroll
            for (int oc = 0; oc < 2; ++oc) {
                int gw = base_w - 4 + 2 * qc + oc;
                float4 out = make_float4(0.f, 0.f, 0.f, 0.f);
                if (gh >= 0 && gh < H1 && gw >= 0 && gw < W1) {
                    float n0 = acc[orr][oc][0], d0 = acc[orr][oc][1];
                    float n1 = acc[orr][oc][2], d1 = acc[orr][oc][3];
                    float c0v = d0 * is0, x0v = n0 * rcpf_(d0 + EPSF) + bb0;
                    float c1v = d1 * is1, x1v = n1 * rcpf_(d1 + EPSF) + bb1;
                    out = make_float4(x0v * c0v, c0v, x1v * c1v, c1v);
                }
                if (oc == 0) A1e[r * 21 + qc] = out;
                else         A1o[r * 21 + qc] = out;
            }
        }
    }
    __syncthreads();   // A1 ready; stage0 data dead -> U4 reusable

    // stage 2: conv2 (CIN=2), 20x36 outputs (origin -2), 10x18=180 quads.
    if (tid < 180) {
        const float is0 = wb[810], is1 = wb[811];
        const float bb0 = b2[0], bb1 = b2[1];
        int qr = tid / 18, qc = tid % 18;
        int r0 = 2 * qr;
        float acc[2][2][4];
        #pragma unroll
        for (int a = 0; a < 2; ++a)
            #pragma unroll
            for (int o = 0; o < 2; ++o)
                #pragma unroll
                for (int k = 0; k < 4; ++k) acc[a][o][k] = 0.f;
        #pragma unroll
        for (int tr = 0; tr < 6; ++tr) {
            const int rr = (r0 + tr) * 21;
            float4 t[6];
            t[0] = A1e[rr + qc];     t[1] = A1o[rr + qc];
            t[2] = A1e[rr + qc + 1]; t[3] = A1o[rr + qc + 1];
            t[4] = A1e[rr + qc + 2]; t[5] = A1o[rr + qc + 2];
            #pragma unroll
            for (int orr = 0; orr < 2; ++orr) {
                const int dh = tr - orr;
                if (dh < 0 || dh > 4) continue;
                #pragma unroll
                for (int dw = 0; dw < 5; ++dw) {
                    const int k = dh * 5 + dw;
                    float wa0 = wb[96 + k],  wc0 = wb[121 + k];
                    float wa1 = wb[146 + k], wc1 = wb[171 + k];
                    #pragma unroll
                    for (int oc = 0; oc < 2; ++oc) {
                        float4 v = t[dw + oc];
                        acc[orr][oc][0] = fmaf(wa0, v.x, fmaf(wc0, v.z, acc[orr][oc][0]));
                        acc[orr][oc][1] = fmaf(wa0, v.y, fmaf(wc0, v.w, acc[orr][oc][1]));
                        acc[orr][oc][2] = fmaf(wa1, v.x, fmaf(wc1, v.z, acc[orr][oc][2]));
                        acc[orr][oc][3] = fmaf(wa1, v.y, fmaf(wc1, v.w, acc[orr][oc][3]));
                    }
                }
            }
        }
        #pragma unroll
        for (int orr = 0; orr < 2; ++orr) {
            int r = r0 + orr;
            int gh = base_h - 2 + r;
            #pragma unroll
            for (int oc = 0; oc < 2; ++oc) {
                int gw = base_w - 2 + 2 * qc + oc;
                float4 out = make_float4(0.f, 0.f, 0.f, 0.f);
                if (gh >= 0 && gh < H1 && gw >= 0 && gw < W1) {
                    float n0 = acc[orr][oc][0], d0 = acc[orr][oc][1];
                    float n1 = acc[orr][oc][2], d1 = acc[orr][oc][3];
                    float c0v = d0 * is0, x0v = n0 * rcpf_(d0 + EPSF) + bb0;
                    float c1v = d1 * is1, x1v = n1 * rcpf_(d1 + EPSF) + bb1;
                    out = make_float4(x0v * c0v, c0v, x1v * c1v, c1v);
                }
                if (oc == 0) U4e[r * 19 + qc] = out;
                else         U4o[r * 19 + qc] = out;
            }
        }
    }
    __syncthreads();

    // stage 3: conv3, 8x16=128 quads; write Apk + pooled P1pk.
    if (tid < 128) {
        const float is0 = wb[812], is1 = wb[813];
        const float bb0 = b3[0], bb1 = b3[1];
        const int pr = tid >> 4, pc = tid & 15;
        const int r0 = 2 * pr;
        float acc[2][2][4];
        #pragma unroll
        for (int a = 0; a < 2; ++a)
            #pragma unroll
            for (int o = 0; o < 2; ++o)
                #pragma unroll
                for (int k = 0; k < 4; ++k) acc[a][o][k] = 0.f;
        #pragma unroll
        for (int tr = 0; tr < 6; ++tr) {
            const int rr = (r0 + tr) * 19;
            float4 t[6];
            t[0] = U4e[rr + pc];     t[1] = U4o[rr + pc];
            t[2] = U4e[rr + pc + 1]; t[3] = U4o[rr + pc + 1];
            t[4] = U4e[rr + pc + 2]; t[5] = U4o[rr + pc + 2];
            #pragma unroll
            for (int orr = 0; orr < 2; ++orr) {
                const int dh = tr - orr;
                if (dh < 0 || dh > 4) continue;
                #pragma unroll
                for (int dw = 0; dw < 5; ++dw) {
                    const int k = dh * 5 + dw;
                    float wa0 = wb[256 + k], wc0 = wb[281 + k];
                    float wa1 = wb[306 + k], wc1 = wb[331 + k];
                    #pragma unroll
                    for (int oc = 0; oc < 2; ++oc) {
                        float4 v = t[dw + oc];
                        acc[orr][oc][0] = fmaf(wa0, v.x, fmaf(wc0, v.z, acc[orr][oc][0]));
                        acc[orr][oc][1] = fmaf(wa0, v.y, fmaf(wc0, v.w, acc[orr][oc][1]));
                        acc[orr][oc][2] = fmaf(wa1, v.x, fmaf(wc1, v.z, acc[orr][oc][2]));
                        acc[orr][oc][3] = fmaf(wa1, v.y, fmaf(wc1, v.w, acc[orr][oc][3]));
                    }
                }
            }
        }
        float xv[2][4], cv[2][4];
        #pragma unroll
        for (int orr = 0; orr < 2; ++orr)
            #pragma unroll
            for (int oc = 0; oc < 2; ++oc) {
                int q = orr * 2 + oc;
                float n0 = acc[orr][oc][0], d0 = acc[orr][oc][1];
                float n1 = acc[orr][oc][2], d1 = acc[orr][oc][3];
                xv[0][q] = n0 * rcpf_(d0 + EPSF) + bb0;
                xv[1][q] = n1 * rcpf_(d1 + EPSF) + bb1;
                cv[0][q] = d0 * is0;
                cv[1][q] = d1 * is1;
            }
        int fh = base_h + r0, fw = base_w + 2 * pc;
        int ph = (base_h >> 1) + pr, pw = (base_w >> 1) + pc;
        uint2 q00 = packpx(xv[0][0], cv[0][0], xv[1][0], cv[1][0]);
        uint2 q01 = packpx(xv[0][1], cv[0][1], xv[1][1], cv[1][1]);
        uint2 q10 = packpx(xv[0][2], cv[0][2], xv[1][2], cv[1][2]);
        uint2 q11 = packpx(xv[0][3], cv[0][3], xv[1][3], cv[1][3]);
        long o0 = (long)b * (H1 * W1) + (long)fh * W1 + fw;
        *reinterpret_cast<uint4*>(Apk + o0)      = make_uint4(q00.x, q00.y, q01.x, q01.y);
        *reinterpret_cast<uint4*>(Apk + o0 + W1) = make_uint4(q10.x, q10.y, q11.x, q11.y);
        // pool per channel (f32 first-max, row-major; value-tracked)
        float cm0 = cv[0][0], xs0 = xv[0][0];
        if (cv[0][1] > cm0) { cm0 = cv[0][1]; xs0 = xv[0][1]; }
        if (cv[0][2] > cm0) { cm0 = cv[0][2]; xs0 = xv[0][2]; }
        if (cv[0][3] > cm0) { cm0 = cv[0][3]; xs0 = xv[0][3]; }
        float cm1 = cv[1][0], xs1 = xv[1][0];
        if (cv[1][1] > cm1) { cm1 = cv[1][1]; xs1 = xv[1][1]; }
        if (cv[1][2] > cm1) { cm1 = cv[1][2]; xs1 = xv[1][2]; }
        if (cv[1][3] > cm1) { cm1 = cv[1][3]; xs1 = xv[1][3]; }
        P1pk[(long)b * (H2 * W2) + (long)ph * W2 + pw] =
            packpx(xs0, cm0 * 0.25f, xs1, cm1 * 0.25f);
    }
}

// ---------------------------------------------------------------------------
// Fused L2, v6: 32x16 tile (same geometry change). LDS 28.3KB -> 5 blocks/CU.
// H2=176 = 11*16 exact; W2=608 = 19*32 exact -> no partial tiles.
// ---------------------------------------------------------------------------
__global__ __launch_bounds__(256) void fused_l2(
    const uint2* __restrict__ P1pk, const float* __restrict__ wb,
    const float* __restrict__ b2, const float* __restrict__ b3,
    uint2* __restrict__ Dpk, uint2* __restrict__ P2pk) {

    __shared__ float4 T0buf[2 * 24 * 21];   // input tile 24x40 halves. 16128 B
    __shared__ float4 T1buf[2 * 20 * 19];   // conv2 out 20x36 halves. 12160 B
    float4* T0e = T0buf; float4* T0o = T0buf + 24 * 21;
    float4* T1e = T1buf; float4* T1o = T1buf + 20 * 19;

    const int tid = threadIdx.x;
    const int base_h = blockIdx.y * TH;
    const int base_w = blockIdx.x * TW;
    const int b = blockIdx.z;
    const long pl = (long)H2 * W2;
    const uint2* ip = P1pk + (long)b * pl;

    // stage 0: 24x40 input tile (origin -4); pixel-pair uint4 loads (gw even).
    for (int i = tid; i < 24 * 20; i += 256) {
        int r = i / 20, cp2 = i % 20;
        int gh = base_h - 4 + r, gw = base_w - 4 + 2 * cp2;
        uint4 pp = make_uint4(0, 0, 0, 0);
        if (gh >= 0 && gh < H2 && gw >= 0 && gw < W2)
            pp = *reinterpret_cast<const uint4*>(ip + (long)gh * W2 + gw);
        T0e[r * 21 + cp2] = unpk(make_uint2(pp.x, pp.y));
        T0o[r * 21 + cp2] = unpk(make_uint2(pp.z, pp.w));
    }
    __syncthreads();

    // conv w2 -> 20x36 (origin -2), 10x18=180 quads.
    if (tid < 180) {
        const float is0 = wb[810], is1 = wb[811];
        const float bb0 = b2[0], bb1 = b2[1];
        int qr = tid / 18, qc = tid % 18;
        int r0 = 2 * qr;
        float acc[2][2][4];
        #pragma unroll
        for (int a = 0; a < 2; ++a)
            #pragma unroll
            for (int o = 0; o < 2; ++o)
                #pragma unroll
                for (int k = 0; k < 4; ++k) acc[a][o][k] = 0.f;
        #pragma unroll
        for (int tr = 0; tr < 6; ++tr) {
            const int rr = (r0 + tr) * 21;
            float4 t[6];
            t[0] = T0e[rr + qc];     t[1] = T0o[rr + qc];
            t[2] = T0e[rr + qc + 1]; t[3] = T0o[rr + qc + 1];
            t[4] = T0e[rr + qc + 2]; t[5] = T0o[rr + qc + 2];
            #pragma unroll
            for (int orr = 0; orr < 2; ++orr) {
                const int dh = tr - orr;
                if (dh < 0 || dh > 4) continue;
                #pragma unroll
                for (int dw = 0; dw < 5; ++dw) {
                    const int k = dh * 5 + dw;
                    float wa0 = wb[96 + k],  wc0 = wb[121 + k];
                    float wa1 = wb[146 + k], wc1 = wb[171 + k];
                    #pragma unroll
                    for (int oc = 0; oc < 2; ++oc) {
                        float4 v = t[dw + oc];
                        acc[orr][oc][0] = fmaf(wa0, v.x, fmaf(wc0, v.z, acc[orr][oc][0]));
                        acc[orr][oc][1] = fmaf(wa0, v.y, fmaf(wc0, v.w, acc[orr][oc][1]));
                        acc[orr][oc][2] = fmaf(wa1, v.x, fmaf(wc1, v.z, acc[orr][oc][2]));
                        acc[orr][oc][3] = fmaf(wa1, v.y, fmaf(wc1, v.w, acc[orr][oc][3]));
                    }
                }
            }
        }
        #pragma unroll
        for (int orr = 0; orr < 2; ++orr) {
            int r = r0 + orr;
            int gh = base_h - 2 + r;
            #pragma unroll
            for (int oc = 0; oc < 2; ++oc) {
                int gw = base_w - 2 + 2 * qc + oc;
                float4 out = make_float4(0.f, 0.f, 0.f, 0.f);
                if (gh >= 0 && gh < H2 && gw >= 0 && gw < W2) {
                    float n0 = acc[orr][oc][0], d0 = acc[orr][oc][1];
                    float n1 = acc[orr][oc][2], d1 = acc[orr][oc][3];
                    float c0v = d0 * is0, x0v = n0 * rcpf_(d0 + EPSF) + bb0;
                    float c1v = d1 * is1, x1v = n1 * rcpf_(d1 + EPSF) + bb1;
                    out = make_float4(x0v * c0v, c0v, x1v * c1v, c1v);
                }
                if (oc == 0) T1e[r * 19 + qc] = out;
                else         T1o[r * 19 + qc] = out;
            }
        }
    }
    __syncthreads();

    // conv w3, 8x16=128 quads; write Dpk + pooled P2pk.
    if (tid < 128) {
        const float is0 = wb[812], is1 = wb[813];
        const float bb0 = b3[0], bb1 = b3[1];
        const int pr = tid >> 4, pc = tid & 15;
        const int r0 = 2 * pr;
        float acc[2][2][4];
        #pragma unroll
        for (int a = 0; a < 2; ++a)
            #pragma unroll
            for (int o = 0; o < 2; ++o)
                #pragma unroll
                for (int k = 0; k < 4; ++k) acc[a][o][k] = 0.f;
        #pragma unroll
        for (int tr = 0; tr < 6; ++tr) {
            const int rr = (r0 + tr) * 19;
            float4 t[6];
            t[0] = T1e[rr + pc];     t[1] = T1o[rr + pc];
            t[2] = T1e[rr + pc + 1]; t[3] = T1o[rr + pc + 1];
            t[4] = T1e[rr + pc + 2]; t[5] = T1o[rr + pc + 2];
            #pragma unroll
            for (int orr = 0; orr < 2; ++orr) {
                const int dh = tr - orr;
                if (dh < 0 || dh > 4) continue;
                #pragma unroll
                for (int dw = 0; dw < 5; ++dw) {
                    const int k = dh * 5 + dw;
                    float wa0 = wb[256 + k], wc0 = wb[281 + k];
                    float wa1 = wb[306 + k], wc1 = wb[331 + k];
                    #pragma unroll
                    for (int oc = 0; oc < 2; ++oc) {
                        float4 v = t[dw + oc];
                        acc[orr][oc][0] = fmaf(wa0, v.x, fmaf(wc0, v.z, acc[orr][oc][0]));
                        acc[orr][oc][1] = fmaf(wa0, v.y, fmaf(wc0, v.w, acc[orr][oc][1]));
                        acc[orr][oc][2] = fmaf(wa1, v.x, fmaf(wc1, v.z, acc[orr][oc][2]));
                        acc[orr][oc][3] = fmaf(wa1, v.y, fmaf(wc1, v.w, acc[orr][oc][3]));
                    }
                }
            }
        }
        int fh = base_h + r0, fw = base_w + 2 * pc;
        {
            float xv[2][4], cv[2][4];
            #pragma unroll
            for (int orr = 0; orr < 2; ++orr)
                #pragma unroll
                for (int oc = 0; oc < 2; ++oc) {
                    int q = orr * 2 + oc;
                    float n0 = acc[orr][oc][0], d0 = acc[orr][oc][1];
                    float n1 = acc[orr][oc][2], d1 = acc[orr][oc][3];
                    xv[0][q] = n0 * rcpf_(d0 + EPSF) + bb0;
                    xv[1][q] = n1 * rcpf_(d1 + EPSF) + bb1;
                    cv[0][q] = d0 * is0;
                    cv[1][q] = d1 * is1;
                }
            uint2 q00 = packpx(xv[0][0], cv[0][0], xv[1][0], cv[1][0]);
            uint2 q01 = packpx(xv[0][1], cv[0][1], xv[1][1], cv[1][1]);
            uint2 q10 = packpx(xv[0][2], cv[0][2], xv[1][2], cv[1][2]);
            uint2 q11 = packpx(xv[0][3], cv[0][3], xv[1][3], cv[1][3]);
            long o0 = (long)b * pl + (long)fh * W2 + fw;
            *reinterpret_cast<uint4*>(Dpk + o0)      = make_uint4(q00.x, q00.y, q01.x, q01.y);
            *reinterpret_cast<uint4*>(Dpk + o0 + W2) = make_uint4(q10.x, q10.y, q11.x, q11.y);
            float cm0 = cv[0][0], xs0 = xv[0][0];
            if (cv[0][1] > cm0) { cm0 = cv[0][1]; xs0 = xv[0][1]; }
            if (cv[0][2] > cm0) { cm0 = cv[0][2]; xs0 = xv[0][2]; }
            if (cv[0][3] > cm0) { cm0 = cv[0][3]; xs0 = xv[0][3]; }
            float cm1 = cv[1][0], xs1 = xv[1][0];
            if (cv[1][1] > cm1) { cm1 = cv[1][1]; xs1 = xv[1][1]; }
            if (cv[1][2] > cm1) { cm1 = cv[1][2]; xs1 = xv[1][2]; }
            if (cv[1][3] > cm1) { cm1 = cv[1][3]; xs1 = xv[1][3]; }
            int ph = (base_h >> 1) + pr, pw = (base_w >> 1) + pc;
            P2pk[(long)b * (H3 * W3) + (long)ph * W3 + pw] =
                packpx(xs0, cm0 * 0.25f, xs1, cm1 * 0.25f);
        }
    }
}

// ---------------------------------------------------------------------------
// Fused L3: P2pk -> conv w2 -> Gpk (full) + pooled P3pk. Deinterleaved LDS.
// ---------------------------------------------------------------------------
__global__ __launch_bounds__(256) void fused_l3(
    const uint2* __restrict__ P2pk, const float* __restrict__ wb,
    const float* __restrict__ b2,
    uint2* __restrict__ Gpk, uint2* __restrict__ P3pk) {

    __shared__ float4 T0buf[2 * 36 * 19];
    float4* T0e = T0buf; float4* T0o = T0buf + 36 * 19;

    const int tid = threadIdx.x;
    const int base_h = blockIdx.y * 32;
    const int base_w = blockIdx.x * 32;
    const int b = blockIdx.z;
    const long pl = (long)H3 * W3;
    const uint2* ip = P2pk + (long)b * pl;

    for (int i = tid; i < 36 * 18; i += 256) {
        int r = i / 18, cp2 = i % 18;
        int gh = base_h - 2 + r, gw = base_w - 2 + 2 * cp2;
        uint4 pp = make_uint4(0, 0, 0, 0);
        if (gh >= 0 && gh < H3 && gw >= 0 && gw < W3)
            pp = *reinterpret_cast<const uint4*>(ip + (long)gh * W3 + gw);
        T0e[r * 19 + cp2] = unpk(make_uint2(pp.x, pp.y));
        T0o[r * 19 + cp2] = unpk(make_uint2(pp.z, pp.w));
    }
    __syncthreads();

    {
        const float is0 = wb[810], is1 = wb[811];
        const float bb0 = b2[0], bb1 = b2[1];
        const int pr = tid >> 4, pc = tid & 15;
        const int r0 = 2 * pr;
        float acc[2][2][4];
        #pragma unroll
        for (int a = 0; a < 2; ++a)
            #pragma unroll
            for (int o = 0; o < 2; ++o)
                #pragma unroll
                for (int k = 0; k < 4; ++k) acc[a][o][k] = 0.f;
        #pragma unroll
        for (int tr = 0; tr < 6; ++tr) {
            const int rr = (r0 + tr) * 19;
            float4 t[6];
            t[0] = T0e[rr + pc];     t[1] = T0o[rr + pc];
            t[2] = T0e[rr + pc + 1]; t[3] = T0o[rr + pc + 1];
            t[4] = T0e[rr + pc + 2]; t[5] = T0o[rr + pc + 2];
            #pragma unroll
            for (int orr = 0; orr < 2; ++orr) {
                const int dh = tr - orr;
                if (dh < 0 || dh > 4) continue;
                #pragma unroll
                for (int dw = 0; dw < 5; ++dw) {
                    const int k = dh * 5 + dw;
                    float wa0 = wb[96 + k],  wc0 = wb[121 + k];
                    float wa1 = wb[146 + k], wc1 = wb[171 + k];
                    #pragma unroll
                    for (int oc = 0; oc < 2; ++oc) {
                        float4 v = t[dw + oc];
                        acc[orr][oc][0] = fmaf(wa0, v.x, fmaf(wc0, v.z, acc[orr][oc][0]));
                        acc[orr][oc][1] = fmaf(wa0, v.y, fmaf(wc0, v.w, acc[orr][oc][1]));
                        acc[orr][oc][2] = fmaf(wa1, v.x, fmaf(wc1, v.z, acc[orr][oc][2]));
                        acc[orr][oc][3] = fmaf(wa1, v.y, fmaf(wc1, v.w, acc[orr][oc][3]));
                    }
                }
            }
        }
        int fh = base_h + r0, fw = base_w + 2 * pc;
        if (fh < H3 && fw < W3) {
            float xv[2][4], cv[2][4];
            #pragma unroll
            for (int orr = 0; orr < 2; ++orr)
                #pragma unroll
                for (int oc = 0; oc < 2; ++oc) {
                    int q = orr * 2 + oc;
                    float n0 = acc[orr][oc][0], d0 = acc[orr][oc][1];
                    float n1 = acc[orr][oc][2], d1 = acc[orr][oc][3];
                    xv[0][q] = n0 * rcpf_(d0 + EPSF) + bb0;
                    xv[1][q] = n1 * rcpf_(d1 + EPSF) + bb1;
                    cv[0][q] = d0 * is0;
                    cv[1][q] = d1 * is1;
                }
            uint2 q00 = packpx(xv[0][0], cv[0][0], xv[1][0], cv[1][0]);
            uint2 q01 = packpx(xv[0][1], cv[0][1], xv[1][1], cv[1][1]);
            uint2 q10 = packpx(xv[0][2], cv[0][2], xv[1][2], cv[1][2]);
            uint2 q11 = packpx(xv[0][3], cv[0][3], xv[1][3], cv[1][3]);
            long o0 = (long)b * pl + (long)fh * W3 + fw;
            *reinterpret_cast<uint4*>(Gpk + o0)      = make_uint4(q00.x, q00.y, q01.x, q01.y);
            *reinterpret_cast<uint4*>(Gpk + o0 + W3) = make_uint4(q10.x, q10.y, q11.x, q11.y);
            float cm0 = cv[0][0], xs0 = xv[0][0];
            if (cv[0][1] > cm0) { cm0 = cv[0][1]; xs0 = xv[0][1]; }
            if (cv[0][2] > cm0) { cm0 = cv[0][2]; xs0 = xv[0][2]; }
            if (cv[0][3] > cm0) { cm0 = cv[0][3]; xs0 = xv[0][3]; }
            float cm1 = cv[1][0], xs1 = xv[1][0];
            if (cv[1][1] > cm1) { cm1 = cv[1][1]; xs1 = xv[1][1]; }
            if (cv[1][2] > cm1) { cm1 = cv[1][2]; xs1 = xv[1][2]; }
            if (cv[1][3] > cm1) { cm1 = cv[1][3]; xs1 = xv[1][3]; }
            int ph = (base_h >> 1) + pr, pw = (base_w >> 1) + pc;
            P3pk[(long)b * (H4 * W4) + (long)ph * W4 + pw] =
                packpx(xs0, cm0 * 0.25f, xs1, cm1 * 0.25f);
        }
    }
}

// ---------------------------------------------------------------------------
// L4 conv: 5x5 pad2 nconv on packed pixels (w2, b2). Per-pixel (small level).
// ---------------------------------------------------------------------------
__global__ void nconv5_pk(const uint2* __restrict__ in, const float* __restrict__ wb,
                          const float* __restrict__ bias, uint2* __restrict__ out,
                          int H, int W) {
    int idx = blockIdx.x * blockDim.x + threadIdx.x;
    int total = B_ * H * W;
    if (idx >= total) return;
    int w = idx % W; int t = idx / W; int h = t % H; int b = t / H;
    const uint2* ip = in + (long)b * H * W;
    float n0 = 0, d0 = 0, n1 = 0, d1 = 0;
    #pragma unroll
    for (int dh = 0; dh < 5; ++dh) {
        int ih = h + dh - 2;
        if (ih < 0 || ih >= H) continue;
        #pragma unroll
        for (int dw = 0; dw < 5; ++dw) {
            int iw = w + dw - 2;
            if (iw < 0 || iw >= W) continue;
            float4 v = unpk(ip[(long)ih * W + iw]);
            const int k = dh * 5 + dw;
            float wa0 = wb[96 + k],  wc0 = wb[121 + k];
            float wa1 = wb[146 + k], wc1 = wb[171 + k];
            n0 = fmaf(wa0, v.x, fmaf(wc0, v.z, n0));
            d0 = fmaf(wa0, v.y, fmaf(wc0, v.w, d0));
            n1 = fmaf(wa1, v.x, fmaf(wc1, v.z, n1));
            d1 = fmaf(wa1, v.y, fmaf(wc1, v.w, d1));
        }
    }
    out[(long)b * H * W + (long)h * W + w] =
        packpx(n0 * rcpf_(d0 + EPSF) + bias[0], d0 * wb[810],
               n1 * rcpf_(d1 + EPSF) + bias[1], d1 * wb[811]);
}

// ---------------------------------------------------------------------------
// Decoder H3: F = nconv(cat(G, up2(I)), w4, b4). Per-pixel packed.
// ---------------------------------------------------------------------------
__global__ void nconv_cat_pk(const uint2* __restrict__ nat, const uint2* __restrict__ up,
                             const float* __restrict__ wb, const float* __restrict__ bias,
                             uint2* __restrict__ out, int H, int W) {
    int idx = blockIdx.x * blockDim.x + threadIdx.x;
    int total = B_ * H * W;
    if (idx >= total) return;
    int Hh = H / 2, Wh = W / 2;
    int w = idx % W; int t = idx / W; int h = t % H; int b = t / H;
    const uint2* np = nat + (long)b * H * W;
    const uint2* upp = up + (long)b * Hh * Wh;
    float n0 = 0, d0 = 0, n1 = 0, d1 = 0;
    #pragma unroll
    for (int dh = 0; dh < 3; ++dh) {
        int ih = h + dh - 1;
        if (ih < 0 || ih >= H) continue;
        #pragma unroll
        for (int dw = 0; dw < 3; ++dw) {
            int iw = w + dw - 1;
            if (iw < 0 || iw >= W) continue;
            float4 aN = unpk(np[(long)ih * W + iw]);
            float4 eU = unpk(upp[(long)(ih >> 1) * Wh + (iw >> 1)]);
            const int k = dh * 3 + dw;
            float na0 = wb[416 + k], nb0 = wb[425 + k], ua0 = wb[434 + k], ub0 = wb[443 + k];
            float na1 = wb[452 + k], nb1 = wb[461 + k], ua1 = wb[470 + k], ub1 = wb[479 + k];
            n0 = fmaf(na0, aN.x, fmaf(nb0, aN.z, fmaf(ua0, eU.x, fmaf(ub0, eU.z, n0))));
            d0 = fmaf(na0, aN.y, fmaf(nb0, aN.w, fmaf(ua0, eU.y, fmaf(ub0, eU.w, d0))));
            n1 = fmaf(na1, aN.x, fmaf(nb1, aN.z, fmaf(ua1, eU.x, fmaf(ub1, eU.z, n1))));
            d1 = fmaf(na1, aN.y, fmaf(nb1, aN.w, fmaf(ua1, eU.y, fmaf(ub1, eU.w, d1))));
        }
    }
    out[(long)b * H * W + (long)h * W + w] =
        packpx(n0 * rcpf_(d0 + EPSF) + bias[0], d0 * wb[814],
               n1 * rcpf_(d1 + EPSF) + bias[1], d1 * wb[815]);
}

// ---------------------------------------------------------------------------
// Decoder H2 tiled (round-5 proven version): register windows a4/e3.
// ---------------------------------------------------------------------------
__global__ __launch_bounds__(256) void nconv_cat_h2t(
    const uint2* __restrict__ Dpk, const uint2* __restrict__ Fpk,
    const float* __restrict__ wb, const float* __restrict__ b5,
    uint2* __restrict__ Epk) {

    __shared__ float4 aTbuf[2 * 34 * 17];
    __shared__ float4 eT[18 * 19];
    float4* aTe = aTbuf; float4* aTo = aTbuf + 34 * 17;

    const int tid = threadIdx.x;
    const int bh = blockIdx.y * 32, bw = blockIdx.x * 32, b = blockIdx.z;
    const int eh0 = (bh - 1) >> 1, ew0 = (bw - 1) >> 1;
    const uint2* dp = Dpk + (long)b * (H2 * W2);
    const uint2* fp = Fpk + (long)b * (H3 * W3);

    for (int i = tid; i < 34 * 17; i += 256) {
        int r = i / 17, cp2 = i % 17;
        int gh = bh - 1 + r;
        int gw0 = bw - 1 + 2 * cp2, gw1 = gw0 + 1;
        uint2 p0 = make_uint2(0, 0), p1 = make_uint2(0, 0);
        if (gh >= 0 && gh < H2) {
            if (gw0 >= 0 && gw0 < W2) p0 = dp[(long)gh * W2 + gw0];
            if (gw1 < W2)             p1 = dp[(long)gh * W2 + gw1];
        }
        aTe[r * 17 + cp2] = unpk(p0);
        aTo[r * 17 + cp2] = unpk(p1);
    }
    for (int i = tid; i < 18 * 18; i += 256) {
        int r = i / 18, c = i % 18;
        int gh = eh0 + r, gw = ew0 + c;
        float4 v = make_float4(0.f, 0.f, 0.f, 0.f);
        if (gh >= 0 && gh < H3 && gw >= 0 && gw < W3)
            v = unpk(fp[(long)gh * W3 + gw]);
        eT[r * 19 + c] = v;
    }
    __syncthreads();

    const int pr = tid >> 4, pc = tid & 15;
    const int r0 = 2 * pr;
    float4 a4[4][4], e3[3][3];
    #pragma unroll
    for (int j = 0; j < 4; ++j) {
        const int rr = (r0 + j) * 17;
        a4[j][0] = aTe[rr + pc];     a4[j][1] = aTo[rr + pc];
        a4[j][2] = aTe[rr + pc + 1]; a4[j][3] = aTo[rr + pc + 1];
    }
    #pragma unroll
    for (int j = 0; j < 3; ++j)
        #pragma unroll
        for (int k = 0; k < 3; ++k) e3[j][k] = eT[(pr + j) * 19 + pc + k];

    float acc[2][2][4];
    #pragma unroll
    for (int a = 0; a < 2; ++a)
        #pragma unroll
        for (int o = 0; o < 2; ++o)
            #pragma unroll
            for (int k = 0; k < 4; ++k) acc[a][o][k] = 0.f;

    #pragma unroll
    for (int orr = 0; orr < 2; ++orr)
        #pragma unroll
        for (int dh = 0; dh < 3; ++dh)
            #pragma unroll
            for (int oc = 0; oc < 2; ++oc)
                #pragma unroll
                for (int dw = 0; dw < 3; ++dw) {
                    float4 aN = a4[orr + dh][oc + dw];
                    float4 eU = e3[(orr + dh + 1) >> 1][(oc + dw + 1) >> 1];
                    const int k = dh * 3 + dw;
                    float na0 = wb[544 + k], nb0 = wb[553 + k], ua0 = wb[562 + k], ub0 = wb[571 + k];
                    float na1 = wb[580 + k], nb1 = wb[589 + k], ua1 = wb[598 + k], ub1 = wb[607 + k];
                    acc[orr][oc][0] = fmaf(na0, aN.x, fmaf(nb0, aN.z, fmaf(ua0, eU.x, fmaf(ub0, eU.z, acc[orr][oc][0]))));
                    acc[orr][oc][1] = fmaf(na0, aN.y, fmaf(nb0, aN.w, fmaf(ua0, eU.y, fmaf(ub0, eU.w, acc[orr][oc][1]))));
                    acc[orr][oc][2] = fmaf(na1, aN.x, fmaf(nb1, aN.z, fmaf(ua1, eU.x, fmaf(ub1, eU.z, acc[orr][oc][2]))));
                    acc[orr][oc][3] = fmaf(na1, aN.y, fmaf(nb1, aN.w, fmaf(ua1, eU.y, fmaf(ub1, eU.w, acc[orr][oc][3]))));
                }

    int fh = bh + r0, fw = bw + 2 * pc;
    if (fh < H2) {
        const float is0 = wb[816], is1 = wb[817];
        const float bb0 = b5[0], bb1 = b5[1];
        float xv[2][4], cv[2][4];
        #pragma unroll
        for (int orr = 0; orr < 2; ++orr)
            #pragma unroll
            for (int oc = 0; oc < 2; ++oc) {
                int q = orr * 2 + oc;
                float n0 = acc[orr][oc][0], d0 = acc[orr][oc][1];
                float n1 = acc[orr][oc][2], d1 = acc[orr][oc][3];
                xv[0][q] = n0 * rcpf_(d0 + EPSF) + bb0;
                xv[1][q] = n1 * rcpf_(d1 + EPSF) + bb1;
                cv[0][q] = d0 * is0;
                cv[1][q] = d1 * is1;
            }
        uint2 q00 = packpx(xv[0][0], cv[0][0], xv[1][0], cv[1][0]);
        uint2 q01 = packpx(xv[0][1], cv[0][1], xv[1][1], cv[1][1]);
        uint2 q10 = packpx(xv[0][2], cv[0][2], xv[1][2], cv[1][2]);
        uint2 q11 = packpx(xv[0][3], cv[0][3], xv[1][3], cv[1][3]);
        long o0 = (long)b * (H2 * W2) + (long)fh * W2 + fw;
        *reinterpret_cast<uint4*>(Epk + o0)      = make_uint4(q00.x, q00.y, q01.x, q01.y);
        *reinterpret_cast<uint4*>(Epk + o0 + W2) = make_uint4(q10.x, q10.y, q11.x, q11.y);
    }
}

// ---------------------------------------------------------------------------
// Final (round-5 proven version): register windows a4/e3; w6 3x3 + w7 1x1.
// ---------------------------------------------------------------------------
__global__ __launch_bounds__(256) void final_tiled(
    const uint2* __restrict__ Apk, const uint2* __restrict__ Epk,
    const float* __restrict__ wb,
    const float* __restrict__ b6g, const float* __restrict__ b7g,
    float* __restrict__ oX, float* __restrict__ oC) {

    __shared__ float4 aTbuf[2 * 34 * 17];
    __shared__ float4 eT[18 * 19];
    float4* aTe = aTbuf; float4* aTo = aTbuf + 34 * 17;

    const int tid = threadIdx.x;
    const int bh = blockIdx.y * 32, bw = blockIdx.x * 32, b = blockIdx.z;
    const int eh0 = (bh - 1) >> 1, ew0 = (bw - 1) >> 1;
    const uint2* ap = Apk + (long)b * (H1 * W1);
    const uint2* ep = Epk + (long)b * (H2 * W2);

    for (int i = tid; i < 34 * 17; i += 256) {
        int r = i / 17, cp2 = i % 17;
        int gh = bh - 1 + r;
        int gw0 = bw - 1 + 2 * cp2, gw1 = gw0 + 1;
        uint2 p0 = make_uint2(0, 0), p1 = make_uint2(0, 0);
        if (gh >= 0 && gh < H1) {
            if (gw0 >= 0 && gw0 < W1) p0 = ap[(long)gh * W1 + gw0];
            if (gw1 < W1)             p1 = ap[(long)gh * W1 + gw1];
        }
        aTe[r * 17 + cp2] = unpk(p0);
        aTo[r * 17 + cp2] = unpk(p1);
    }
    for (int i = tid; i < 18 * 18; i += 256) {
        int r = i / 18, c = i % 18;
        int gh = eh0 + r, gw = ew0 + c;
        float4 v = make_float4(0.f, 0.f, 0.f, 0.f);
        if (gh >= 0 && gh < H2 && gw >= 0 && gw < W2)
            v = unpk(ep[(long)gh * W2 + gw]);
        eT[r * 19 + c] = v;
    }
    __syncthreads();

    const int pr = tid >> 4, pc = tid & 15;
    const int r0 = 2 * pr;
    float4 a4[4][4], e3[3][3];
    #pragma unroll
    for (int j = 0; j < 4; ++j) {
        const int rr = (r0 + j) * 17;
        a4[j][0] = aTe[rr + pc];     a4[j][1] = aTo[rr + pc];
        a4[j][2] = aTe[rr + pc + 1]; a4[j][3] = aTo[rr + pc + 1];
    }
    #pragma unroll
    for (int j = 0; j < 3; ++j)
        #pragma unroll
        for (int k = 0; k < 3; ++k) e3[j][k] = eT[(pr + j) * 19 + pc + k];

    float acc[2][2][4];
    #pragma unroll
    for (int a = 0; a < 2; ++a)
        #pragma unroll
        for (int o = 0; o < 2; ++o)
            #pragma unroll
            for (int k = 0; k < 4; ++k) acc[a][o][k] = 0.f;

    // w6 layout: up (E) = ci 0-1, native (A) = ci 2-3.
    #pragma unroll
    for (int orr = 0; orr < 2; ++orr)
        #pragma unroll
        for (int dh = 0; dh < 3; ++dh)
            #pragma unroll
            for (int oc = 0; oc < 2; ++oc)
                #pragma unroll
                for (int dw = 0; dw < 3; ++dw) {
                    float4 aN = a4[orr + dh][oc + dw];
                    float4 eU = e3[(orr + dh + 1) >> 1][(oc + dw + 1) >> 1];
                    const int k = dh * 3 + dw;
                    float ua0 = wb[672 + k], ub0 = wb[681 + k], na0 = wb[690 + k], nb0 = wb[699 + k];
                    float ua1 = wb[708 + k], ub1 = wb[717 + k], na1 = wb[726 + k], nb1 = wb[735 + k];
                    acc[orr][oc][0] = fmaf(ua0, eU.x, fmaf(ub0, eU.z, fmaf(na0, aN.x, fmaf(nb0, aN.z, acc[orr][oc][0]))));
                    acc[orr][oc][1] = fmaf(ua0, eU.y, fmaf(ub0, eU.w, fmaf(na0, aN.y, fmaf(nb0, aN.w, acc[orr][oc][1]))));
                    acc[orr][oc][2] = fmaf(ua1, eU.x, fmaf(ub1, eU.z, fmaf(na1, aN.x, fmaf(nb1, aN.z, acc[orr][oc][2]))));
                    acc[orr][oc][3] = fmaf(ua1, eU.y, fmaf(ub1, eU.w, fmaf(na1, aN.y, fmaf(nb1, aN.w, acc[orr][oc][3]))));
                }

    const float is60 = wb[818], is61 = wb[819];
    const float bb60 = b6g[0], bb61 = b6g[1];
    const float w70 = wb[800], w71 = wb[801];
    const float is7 = wb[820], bb7 = b7g[0];
    float ox[2][2], ocv[2][2];
    #pragma unroll
    for (int orr = 0; orr < 2; ++orr)
        #pragma unroll
        for (int oc = 0; oc < 2; ++oc) {
            float n0 = acc[orr][oc][0], d0 = acc[orr][oc][1];
            float n1 = acc[orr][oc][2], d1 = acc[orr][oc][3];
            float x0v = n0 * rcpf_(d0 + EPSF) + bb60;
            float x1v = n1 * rcpf_(d1 + EPSF) + bb61;
            float c0v = d0 * is60, c1v = d1 * is61;
            float den7 = fmaf(w70, c0v, w71 * c1v);
            float nom7 = fmaf(w70, x0v * c0v, w71 * (x1v * c1v));
            ox[orr][oc] = nom7 * rcpf_(den7 + EPSF) + bb7;
            ocv[orr][oc] = den7 * is7;
        }
    long o = (long)b * (H1 * W1) + (long)(bh + r0) * W1 + (bw + 2 * pc);
    *reinterpret_cast<float2*>(oX + o)      = make_float2(ox[0][0], ox[0][1]);
    *reinterpret_cast<float2*>(oX + o + W1) = make_float2(ox[1][0], ox[1][1]);
    *reinterpret_cast<float2*>(oC + o)      = make_float2(ocv[0][0], ocv[0][1]);
    *reinterpret_cast<float2*>(oC + o + W1) = make_float2(ocv[1][0], ocv[1][1]);
}

extern "C" void kernel_launch(void* const* d_in, const int* in_sizes, int n_in,
                              void* d_out, int out_size, void* d_ws, size_t ws_size,
                              hipStream_t stream) {
    const float* x0 = (const float*)d_in[0];
    const float* c0 = (const float*)d_in[1];
    const float* w1 = (const float*)d_in[2];
    const float* b1 = (const float*)d_in[3];
    const float* w2 = (const float*)d_in[4];
    const float* b2 = (const float*)d_in[5];
    const float* w3 = (const float*)d_in[6];
    const float* b3 = (const float*)d_in[7];
    const float* w4 = (const float*)d_in[8];
    const float* b4 = (const float*)d_in[9];
    const float* w5 = (const float*)d_in[10];
    const float* b5 = (const float*)d_in[11];
    const float* w6 = (const float*)d_in[12];
    const float* b6 = (const float*)d_in[13];
    const float* w7 = (const float*)d_in[14];
    const float* b7 = (const float*)d_in[15];

    const long N1 = (long)B_ * H1 * W1;     // 6,848,512 pixels (full res)
    const long N2 = N1 / 4, N3 = N1 / 16, N4 = N1 / 64;

    // ws: [wb 4KB][Apk 8*N1][Epk 8*N2] ~ 68.5 MB
    float* wb = (float*)d_ws;
    uint2* Apk = (uint2*)((char*)d_ws + 4096);
    uint2* Epk = Apk + N1;

    // d_out (N1 uint2 capacity) as packed scratch; final pass reads only ws.
    uint2* R = (uint2*)d_out;
    uint2* P1pk = R;                 // N2
    uint2* Dpk  = R + N2;            // N2
    uint2* P2pk = R + 2 * N2;        // N3
    uint2* Gpk  = P2pk + N3;         // N3
    uint2* P3pk = Gpk + N3;          // N4
    uint2* Ipk  = P3pk + N4;         // N4
    uint2* Fpk  = Ipk + N4;          // N3

    float* oX = (float*)d_out;
    float* oC = oX + N1;

    prep_weights<<<1, 256, 0, stream>>>(w1, w2, w3, w4, w5, w6, w7, wb);

    dim3 gridF(W1 / TW, H1 / TH, B_);               // 38 x 22 x 16
    fused_l1pool<<<gridF, 256, 0, stream>>>(x0, c0, wb, b1, b2, b3, Apk, P1pk);

    dim3 gridL2(W2 / TW, H2 / TH, B_);              // 19 x 11 x 16
    fused_l2<<<gridL2, 256, 0, stream>>>(P1pk, wb, b2, b3, Dpk, P2pk);

    dim3 gridL3((W3 + 31) / 32, (H3 + 31) / 32, B_); // 10 x 3 x 16
    fused_l3<<<gridL3, 256, 0, stream>>>(P2pk, wb, b2, Gpk, P3pk);

    const int g4 = (B_ * H4 * W4 + 255) / 256;
    nconv5_pk<<<g4, 256, 0, stream>>>(P3pk, wb, b2, Ipk, H4, W4);   // I = x4,c4

    const int g3 = (B_ * H3 * W3 + 255) / 256;
    nconv_cat_pk<<<g3, 256, 0, stream>>>(Gpk, Ipk, wb, b4, Fpk, H3, W3);  // F = x34

    dim3 gridH2(W2 / 32, (H2 + 31) / 32, B_);       // 19 x 6 x 16
    nconv_cat_h2t<<<gridH2, 256, 0, stream>>>(Dpk, Fpk, wb, b5, Epk);     // E = x23 (ws)

    dim3 gridL(W1 / 32, H1 / 32, B_);               // 38 x 11 x 16
    final_tiled<<<gridL, 256, 0, stream>>>(Apk, Epk, wb, b6, b7, oX, oC);
}

// Round 9
// 429.890 us; speedup vs baseline: 1.5135x; 1.5135x over previous
//
#include <hip/hip_runtime.h>
#include <hip/hip_bf16.h>

#define EPSF 1e-20f
typedef __hip_bfloat16 bf16;
typedef unsigned int u32;

__device__ __forceinline__ float rcpf_(float v) { return __builtin_amdgcn_rcpf(v); }
__device__ __forceinline__ float bits2f(u32 b) { union { u32 i; float f; } u; u.i = b; return u.f; }
__device__ __forceinline__ float lo2f(u32 v) { return bits2f(v << 16); }
__device__ __forceinline__ float hi2f(u32 v) { return bits2f(v & 0xffff0000u); }
__device__ __forceinline__ u32 f2us(float f) {
    bf16 h = __float2bfloat16(f);
    unsigned short s;
    __builtin_memcpy(&s, &h, 2);
    return (u32)s;
}
// pixel pack: (x0,c0,x1,c1) as 4x bf16 in a uint2
__device__ __forceinline__ uint2 packpx(float x0, float c0, float x1, float c1) {
    return make_uint2(f2us(x0) | (f2us(c0) << 16), f2us(x1) | (f2us(c1) << 16));
}
// unpack to (p0,c0,p1,c1) with p = x*c
__device__ __forceinline__ float4 unpk(uint2 v) {
    float x0 = lo2f(v.x), c0 = hi2f(v.x), x1 = lo2f(v.y), c1 = hi2f(v.y);
    return make_float4(x0 * c0, c0, x1 * c1, c1);
}

// ---- problem dims (fixed by setup_inputs) ----
#define B_ 16
#define H1 352
#define W1 1216
#define H2 176
#define W2 608
#define H3 88
#define W3 304
#define H4 44
#define W4 152

// ---------------------------------------------------------------------------
// Weight prep: w = softplus(10*p)/10, per-out-ch kernel sums + inverse sums.
// Sums parallelized: 13 threads each own one (layer, out-ch) pair (identical
// per-sum arithmetic/order as serial version; verified R7/R8, same absmax).
// wb floats: wt1@0(50) s1@64 | wt2@96(100) s2@224 | wt3@256(100) s3@384 |
// wt4@416(72) s4@512 | wt5@544(72) s5@640 | wt6@672(72) s6@768 |
// wt7@800(2) s7@804 | is1@808 is2@810 is3@812 is4@814 is5@816 is6@818 is7@820
// ---------------------------------------------------------------------------
__global__ void prep_weights(const float* w1, const float* w2, const float* w3,
                             const float* w4, const float* w5, const float* w6,
                             const float* w7, float* wb) {
    const float* ptrs[7] = {w1, w2, w3, w4, w5, w6, w7};
    const int ns[7]   = {50, 100, 100, 72, 72, 72, 2};
    const int offs[7] = {0, 96, 256, 416, 544, 672, 800};
    for (int it = 0; it < 7; ++it)
        for (int i = threadIdx.x; i < ns[it]; i += blockDim.x) {
            float z = 10.f * ptrs[it][i];
            float sp = (z > 20.f) ? z : log1pf(expf(z));
            wb[offs[it] + i] = sp * 0.1f;
        }
    __syncthreads();
    if (threadIdx.x < 13) {
        const int t = threadIdx.x;
        const int it = (t == 12) ? 6 : (t >> 1);
        const int o  = (t == 12) ? 0 : (t & 1);
        const int offs2[7] = {0, 96, 256, 416, 544, 672, 800};
        const int klen2[7] = {25, 50, 50, 36, 36, 36, 2};
        const int soff2[7] = {64, 224, 384, 512, 640, 768, 804};
        float s = 0.f;
        for (int i = 0; i < klen2[it]; ++i) s += wb[offs2[it] + o * klen2[it] + i];
        wb[soff2[it] + o] = s;
        wb[808 + t] = 1.f / s;     // t=0..11 -> 808..819 (is1..is6), t=12 -> 820 (is7)
    }
}

// ---------------------------------------------------------------------------
// Fused L1 encoder + pool (round-5 PROVEN version, 422us config): 256 thr,
// 32x32 tile, even/odd column-deinterleaved LDS, lane-stride-1 window reads.
// Occupancy is HW-pinned at ~33% regardless of LDS (R6/R8 falsifiers) --
// do NOT shrink tile or grow block; 32x32 maximizes compute/halo.
// ---------------------------------------------------------------------------
#define TDIM 32

__global__ __launch_bounds__(256) void fused_l1pool(
    const float* __restrict__ x0g, const float* __restrict__ c0g,
    const float* __restrict__ wb,
    const float* __restrict__ b1, const float* __restrict__ b2, const float* __restrict__ b3,
    uint2* __restrict__ Apk, uint2* __restrict__ P1pk) {

    __shared__ float4 A1buf[2 * 40 * 21];   // stage1 out halves (stride 21). 26880 B
    __shared__ float4 U4buf[2 * 36 * 19];   // stage0 (float2 view) / stage2 out. 21888 B
    float4* A1e = A1buf;            float4* A1o = A1buf + 40 * 21;
    float4* U4e = U4buf;            float4* U4o = U4buf + 36 * 19;
    float2* U2e = (float2*)U4buf;   float2* U2o = U2e + 44 * 23;   // 16192 B <= 21888

    const int tid = threadIdx.x;
    const int base_h = blockIdx.y * TDIM;
    const int base_w = blockIdx.x * TDIM;
    const int b = blockIdx.z;
    const float* xp = x0g + (long)b * (H1 * W1);
    const float* cpg = c0g + (long)b * (H1 * W1);

    // stage 0: 44x44 (p,c) tile at origin (-6,-6); column-pair float2 loads.
    for (int i = tid; i < 44 * 22; i += 256) {
        int r = i / 22, cp2 = i % 22;
        int gh = base_h - 6 + r, gw = base_w - 6 + 2 * cp2;
        float2 xv = make_float2(0.f, 0.f), cv = make_float2(0.f, 0.f);
        if (gh >= 0 && gh < H1 && gw >= 0 && gw < W1) {
            long o = (long)gh * W1 + gw;
            xv = *reinterpret_cast<const float2*>(xp + o);
            cv = *reinterpret_cast<const float2*>(cpg + o);
        }
        U2e[r * 23 + cp2] = make_float2(xv.x * cv.x, cv.x);
        U2o[r * 23 + cp2] = make_float2(xv.y * cv.y, cv.y);
    }
    __syncthreads();

    // stage 1: conv1 (CIN=1), 40x40 outputs (origin -4), 20x20 quads.
    {
        const float is0 = wb[808], is1 = wb[809];
        const float bb0 = b1[0], bb1 = b1[1];
        for (int i = tid; i < 400; i += 256) {
            int qr = i / 20, qc = i % 20;
            int r0 = 2 * qr;
            float acc[2][2][4];
            #pragma unroll
            for (int a = 0; a < 2; ++a)
                #pragma unroll
                for (int o = 0; o < 2; ++o)
                    #pragma unroll
                    for (int k = 0; k < 4; ++k) acc[a][o][k] = 0.f;
            #pragma unroll
            for (int tr = 0; tr < 6; ++tr) {
                const int rr = (r0 + tr) * 23;
                float2 t[6];
                t[0] = U2e[rr + qc];     t[1] = U2o[rr + qc];
                t[2] = U2e[rr + qc + 1]; t[3] = U2o[rr + qc + 1];
                t[4] = U2e[rr + qc + 2]; t[5] = U2o[rr + qc + 2];
                #pragma unroll
                for (int orr = 0; orr < 2; ++orr) {
                    const int dh = tr - orr;
                    if (dh < 0 || dh > 4) continue;
                    #pragma unroll
                    for (int dw = 0; dw < 5; ++dw) {
                        float wA = wb[dh * 5 + dw];
                        float wB = wb[25 + dh * 5 + dw];
                        #pragma unroll
                        for (int oc = 0; oc < 2; ++oc) {
                            float2 v = t[dw + oc];
                            acc[orr][oc][0] = fmaf(wA, v.x, acc[orr][oc][0]);
                            acc[orr][oc][1] = fmaf(wA, v.y, acc[orr][oc][1]);
                            acc[orr][oc][2] = fmaf(wB, v.x, acc[orr][oc][2]);
                            acc[orr][oc][3] = fmaf(wB, v.y, acc[orr][oc][3]);
                        }
                    }
                }
            }
            #pragma unroll
            for (int orr = 0; orr < 2; ++orr) {
                int r = r0 + orr;
                int gh = base_h - 4 + r;
                #pragma unroll
                for (int oc = 0; oc < 2; ++oc) {
                    int gw = base_w - 4 + 2 * qc + oc;
                    float4 out = make_float4(0.f, 0.f, 0.f, 0.f);
                    if (gh >= 0 && gh < H1 && gw >= 0 && gw < W1) {
                        float n0 = acc[orr][oc][0], d0 = acc[orr][oc][1];
                        float n1 = acc[orr][oc][2], d1 = acc[orr][oc][3];
                        float c0v = d0 * is0, x0v = n0 * rcpf_(d0 + EPSF) + bb0;
                        float c1v = d1 * is1, x1v = n1 * rcpf_(d1 + EPSF) + bb1;
                        out = make_float4(x0v * c0v, c0v, x1v * c1v, c1v);
                    }
                    if (oc == 0) A1e[r * 21 + qc] = out;
                    else         A1o[r * 21 + qc] = out;
                }
            }
        }
    }
    __syncthreads();   // A1 ready; stage0 data dead -> U4 reusable

    // stage 2: conv2 (CIN=2), 36x36 outputs (origin -2), 18x18 quads.
    {
        const float is0 = wb[810], is1 = wb[811];
        const float bb0 = b2[0], bb1 = b2[1];
        for (int i = tid; i < 324; i += 256) {
            int qr = i / 18, qc = i % 18;
            int r0 = 2 * qr;
            float acc[2][2][4];
            #pragma unroll
            for (int a = 0; a < 2; ++a)
                #pragma unroll
                for (int o = 0; o < 2; ++o)
                    #pragma unroll
                    for (int k = 0; k < 4; ++k) acc[a][o][k] = 0.f;
            #pragma unroll
            for (int tr = 0; tr < 6; ++tr) {
                const int rr = (r0 + tr) * 21;
                float4 t[6];
                t[0] = A1e[rr + qc];     t[1] = A1o[rr + qc];
                t[2] = A1e[rr + qc + 1]; t[3] = A1o[rr + qc + 1];
                t[4] = A1e[rr + qc + 2]; t[5] = A1o[rr + qc + 2];
                #pragma unroll
                for (int orr = 0; orr < 2; ++orr) {
                    const int dh = tr - orr;
                    if (dh < 0 || dh > 4) continue;
                    #pragma unroll
                    for (int dw = 0; dw < 5; ++dw) {
                        const int k = dh * 5 + dw;
                        float wa0 = wb[96 + k],  wc0 = wb[121 + k];
                        float wa1 = wb[146 + k], wc1 = wb[171 + k];
                        #pragma unroll
                        for (int oc = 0; oc < 2; ++oc) {
                            float4 v = t[dw + oc];
                            acc[orr][oc][0] = fmaf(wa0, v.x, fmaf(wc0, v.z, acc[orr][oc][0]));
                            acc[orr][oc][1] = fmaf(wa0, v.y, fmaf(wc0, v.w, acc[orr][oc][1]));
                            acc[orr][oc][2] = fmaf(wa1, v.x, fmaf(wc1, v.z, acc[orr][oc][2]));
                            acc[orr][oc][3] = fmaf(wa1, v.y, fmaf(wc1, v.w, acc[orr][oc][3]));
                        }
                    }
                }
            }
            #pragma unroll
            for (int orr = 0; orr < 2; ++orr) {
                int r = r0 + orr;
                int gh = base_h - 2 + r;
                #pragma unroll
                for (int oc = 0; oc < 2; ++oc) {
                    int gw = base_w - 2 + 2 * qc + oc;
                    float4 out = make_float4(0.f, 0.f, 0.f, 0.f);
                    if (gh >= 0 && gh < H1 && gw >= 0 && gw < W1) {
                        float n0 = acc[orr][oc][0], d0 = acc[orr][oc][1];
                        float n1 = acc[orr][oc][2], d1 = acc[orr][oc][3];
                        float c0v = d0 * is0, x0v = n0 * rcpf_(d0 + EPSF) + bb0;
                        float c1v = d1 * is1, x1v = n1 * rcpf_(d1 + EPSF) + bb1;
                        out = make_float4(x0v * c0v, c0v, x1v * c1v, c1v);
                    }
                    if (oc == 0) U4e[r * 19 + qc] = out;
                    else         U4o[r * 19 + qc] = out;
                }
            }
        }
    }
    __syncthreads();

    // stage 3: conv3, one 2x2 quad per thread; write Apk + pooled P1pk.
    {
        const float is0 = wb[812], is1 = wb[813];
        const float bb0 = b3[0], bb1 = b3[1];
        const int pr = tid >> 4, pc = tid & 15;
        const int r0 = 2 * pr;
        float acc[2][2][4];
        #pragma unroll
        for (int a = 0; a < 2; ++a)
            #pragma unroll
            for (int o = 0; o < 2; ++o)
                #pragma unroll
                for (int k = 0; k < 4; ++k) acc[a][o][k] = 0.f;
        #pragma unroll
        for (int tr = 0; tr < 6; ++tr) {
            const int rr = (r0 + tr) * 19;
            float4 t[6];
            t[0] = U4e[rr + pc];     t[1] = U4o[rr + pc];
            t[2] = U4e[rr + pc + 1]; t[3] = U4o[rr + pc + 1];
            t[4] = U4e[rr + pc + 2]; t[5] = U4o[rr + pc + 2];
            #pragma unroll
            for (int orr = 0; orr < 2; ++orr) {
                const int dh = tr - orr;
                if (dh < 0 || dh > 4) continue;
                #pragma unroll
                for (int dw = 0; dw < 5; ++dw) {
                    const int k = dh * 5 + dw;
                    float wa0 = wb[256 + k], wc0 = wb[281 + k];
                    float wa1 = wb[306 + k], wc1 = wb[331 + k];
                    #pragma unroll
                    for (int oc = 0; oc < 2; ++oc) {
                        float4 v = t[dw + oc];
                        acc[orr][oc][0] = fmaf(wa0, v.x, fmaf(wc0, v.z, acc[orr][oc][0]));
                        acc[orr][oc][1] = fmaf(wa0, v.y, fmaf(wc0, v.w, acc[orr][oc][1]));
                        acc[orr][oc][2] = fmaf(wa1, v.x, fmaf(wc1, v.z, acc[orr][oc][2]));
                        acc[orr][oc][3] = fmaf(wa1, v.y, fmaf(wc1, v.w, acc[orr][oc][3]));
                    }
                }
            }
        }
        float xv[2][4], cv[2][4];
        #pragma unroll
        for (int orr = 0; orr < 2; ++orr)
            #pragma unroll
            for (int oc = 0; oc < 2; ++oc) {
                int q = orr * 2 + oc;
                float n0 = acc[orr][oc][0], d0 = acc[orr][oc][1];
                float n1 = acc[orr][oc][2], d1 = acc[orr][oc][3];
                xv[0][q] = n0 * rcpf_(d0 + EPSF) + bb0;
                xv[1][q] = n1 * rcpf_(d1 + EPSF) + bb1;
                cv[0][q] = d0 * is0;
                cv[1][q] = d1 * is1;
            }
        int fh = base_h + r0, fw = base_w + 2 * pc;
        int ph = (base_h >> 1) + pr, pw = (base_w >> 1) + pc;
        uint2 q00 = packpx(xv[0][0], cv[0][0], xv[1][0], cv[1][0]);
        uint2 q01 = packpx(xv[0][1], cv[0][1], xv[1][1], cv[1][1]);
        uint2 q10 = packpx(xv[0][2], cv[0][2], xv[1][2], cv[1][2]);
        uint2 q11 = packpx(xv[0][3], cv[0][3], xv[1][3], cv[1][3]);
        long o0 = (long)b * (H1 * W1) + (long)fh * W1 + fw;
        *reinterpret_cast<uint4*>(Apk + o0)      = make_uint4(q00.x, q00.y, q01.x, q01.y);
        *reinterpret_cast<uint4*>(Apk + o0 + W1) = make_uint4(q10.x, q10.y, q11.x, q11.y);
        // pool per channel (f32 first-max, row-major; value-tracked)
        float cm0 = cv[0][0], xs0 = xv[0][0];
        if (cv[0][1] > cm0) { cm0 = cv[0][1]; xs0 = xv[0][1]; }
        if (cv[0][2] > cm0) { cm0 = cv[0][2]; xs0 = xv[0][2]; }
        if (cv[0][3] > cm0) { cm0 = cv[0][3]; xs0 = xv[0][3]; }
        float cm1 = cv[1][0], xs1 = xv[1][0];
        if (cv[1][1] > cm1) { cm1 = cv[1][1]; xs1 = xv[1][1]; }
        if (cv[1][2] > cm1) { cm1 = cv[1][2]; xs1 = xv[1][2]; }
        if (cv[1][3] > cm1) { cm1 = cv[1][3]; xs1 = xv[1][3]; }
        P1pk[(long)b * (H2 * W2) + (long)ph * W2 + pw] =
            packpx(xs0, cm0 * 0.25f, xs1, cm1 * 0.25f);
    }
}

// ---------------------------------------------------------------------------
// Fused L2 (round-5 proven): P1pk -> conv w2 -> conv w3 -> Dpk + pooled P2pk.
// ---------------------------------------------------------------------------
__global__ __launch_bounds__(256) void fused_l2(
    const uint2* __restrict__ P1pk, const float* __restrict__ wb,
    const float* __restrict__ b2, const float* __restrict__ b3,
    uint2* __restrict__ Dpk, uint2* __restrict__ P2pk) {

    __shared__ float4 T0buf[2 * 40 * 21];
    __shared__ float4 T1buf[2 * 36 * 19];
    float4* T0e = T0buf; float4* T0o = T0buf + 40 * 21;
    float4* T1e = T1buf; float4* T1o = T1buf + 36 * 19;

    const int tid = threadIdx.x;
    const int base_h = blockIdx.y * 32;
    const int base_w = blockIdx.x * 32;
    const int b = blockIdx.z;
    const long pl = (long)H2 * W2;
    const uint2* ip = P1pk + (long)b * pl;

    // stage 0: 40x40 input tile (origin -4); pixel-pair uint4 loads (gw even).
    for (int i = tid; i < 40 * 20; i += 256) {
        int r = i / 20, cp2 = i % 20;
        int gh = base_h - 4 + r, gw = base_w - 4 + 2 * cp2;
        uint4 pp = make_uint4(0, 0, 0, 0);
        if (gh >= 0 && gh < H2 && gw >= 0 && gw < W2)
            pp = *reinterpret_cast<const uint4*>(ip + (long)gh * W2 + gw);
        T0e[r * 21 + cp2] = unpk(make_uint2(pp.x, pp.y));
        T0o[r * 21 + cp2] = unpk(make_uint2(pp.z, pp.w));
    }
    __syncthreads();

    // conv w2 -> 36x36 (origin -2), 18x18 quads.
    {
        const float is0 = wb[810], is1 = wb[811];
        const float bb0 = b2[0], bb1 = b2[1];
        for (int i = tid; i < 324; i += 256) {
            int qr = i / 18, qc = i % 18;
            int r0 = 2 * qr;
            float acc[2][2][4];
            #pragma unroll
            for (int a = 0; a < 2; ++a)
                #pragma unroll
                for (int o = 0; o < 2; ++o)
                    #pragma unroll
                    for (int k = 0; k < 4; ++k) acc[a][o][k] = 0.f;
            #pragma unroll
            for (int tr = 0; tr < 6; ++tr) {
                const int rr = (r0 + tr) * 21;
                float4 t[6];
                t[0] = T0e[rr + qc];     t[1] = T0o[rr + qc];
                t[2] = T0e[rr + qc + 1]; t[3] = T0o[rr + qc + 1];
                t[4] = T0e[rr + qc + 2]; t[5] = T0o[rr + qc + 2];
                #pragma unroll
                for (int orr = 0; orr < 2; ++orr) {
                    const int dh = tr - orr;
                    if (dh < 0 || dh > 4) continue;
                    #pragma unroll
                    for (int dw = 0; dw < 5; ++dw) {
                        const int k = dh * 5 + dw;
                        float wa0 = wb[96 + k],  wc0 = wb[121 + k];
                        float wa1 = wb[146 + k], wc1 = wb[171 + k];
                        #pragma unroll
                        for (int oc = 0; oc < 2; ++oc) {
                            float4 v = t[dw + oc];
                            acc[orr][oc][0] = fmaf(wa0, v.x, fmaf(wc0, v.z, acc[orr][oc][0]));
                            acc[orr][oc][1] = fmaf(wa0, v.y, fmaf(wc0, v.w, acc[orr][oc][1]));
                            acc[orr][oc][2] = fmaf(wa1, v.x, fmaf(wc1, v.z, acc[orr][oc][2]));
                            acc[orr][oc][3] = fmaf(wa1, v.y, fmaf(wc1, v.w, acc[orr][oc][3]));
                        }
                    }
                }
            }
            #pragma unroll
            for (int orr = 0; orr < 2; ++orr) {
                int r = r0 + orr;
                int gh = base_h - 2 + r;
                #pragma unroll
                for (int oc = 0; oc < 2; ++oc) {
                    int gw = base_w - 2 + 2 * qc + oc;
                    float4 out = make_float4(0.f, 0.f, 0.f, 0.f);
                    if (gh >= 0 && gh < H2 && gw >= 0 && gw < W2) {
                        float n0 = acc[orr][oc][0], d0 = acc[orr][oc][1];
                        float n1 = acc[orr][oc][2], d1 = acc[orr][oc][3];
                        float c0v = d0 * is0, x0v = n0 * rcpf_(d0 + EPSF) + bb0;
                        float c1v = d1 * is1, x1v = n1 * rcpf_(d1 + EPSF) + bb1;
                        out = make_float4(x0v * c0v, c0v, x1v * c1v, c1v);
                    }
                    if (oc == 0) T1e[r * 19 + qc] = out;
                    else         T1o[r * 19 + qc] = out;
                }
            }
        }
    }
    __syncthreads();

    // conv w3 per quad; write Dpk + pooled P2pk.
    {
        const float is0 = wb[812], is1 = wb[813];
        const float bb0 = b3[0], bb1 = b3[1];
        const int pr = tid >> 4, pc = tid & 15;
        const int r0 = 2 * pr;
        float acc[2][2][4];
        #pragma unroll
        for (int a = 0; a < 2; ++a)
            #pragma unroll
            for (int o = 0; o < 2; ++o)
                #pragma unroll
                for (int k = 0; k < 4; ++k) acc[a][o][k] = 0.f;
        #pragma unroll
        for (int tr = 0; tr < 6; ++tr) {
            const int rr = (r0 + tr) * 19;
            float4 t[6];
            t[0] = T1e[rr + pc];     t[1] = T1o[rr + pc];
            t[2] = T1e[rr + pc + 1]; t[3] = T1o[rr + pc + 1];
            t[4] = T1e[rr + pc + 2]; t[5] = T1o[rr + pc + 2];
            #pragma unroll
            for (int orr = 0; orr < 2; ++orr) {
                const int dh = tr - orr;
                if (dh < 0 || dh > 4) continue;
                #pragma unroll
                for (int dw = 0; dw < 5; ++dw) {
                    const int k = dh * 5 + dw;
                    float wa0 = wb[256 + k], wc0 = wb[281 + k];
                    float wa1 = wb[306 + k], wc1 = wb[331 + k];
                    #pragma unroll
                    for (int oc = 0; oc < 2; ++oc) {
                        float4 v = t[dw + oc];
                        acc[orr][oc][0] = fmaf(wa0, v.x, fmaf(wc0, v.z, acc[orr][oc][0]));
                        acc[orr][oc][1] = fmaf(wa0, v.y, fmaf(wc0, v.w, acc[orr][oc][1]));
                        acc[orr][oc][2] = fmaf(wa1, v.x, fmaf(wc1, v.z, acc[orr][oc][2]));
                        acc[orr][oc][3] = fmaf(wa1, v.y, fmaf(wc1, v.w, acc[orr][oc][3]));
                    }
                }
            }
        }
        int fh = base_h + r0, fw = base_w + 2 * pc;
        if (fh < H2) {
            float xv[2][4], cv[2][4];
            #pragma unroll
            for (int orr = 0; orr < 2; ++orr)
                #pragma unroll
                for (int oc = 0; oc < 2; ++oc) {
                    int q = orr * 2 + oc;
                    float n0 = acc[orr][oc][0], d0 = acc[orr][oc][1];
                    float n1 = acc[orr][oc][2], d1 = acc[orr][oc][3];
                    xv[0][q] = n0 * rcpf_(d0 + EPSF) + bb0;
                    xv[1][q] = n1 * rcpf_(d1 + EPSF) + bb1;
                    cv[0][q] = d0 * is0;
                    cv[1][q] = d1 * is1;
                }
            uint2 q00 = packpx(xv[0][0], cv[0][0], xv[1][0], cv[1][0]);
            uint2 q01 = packpx(xv[0][1], cv[0][1], xv[1][1], cv[1][1]);
            uint2 q10 = packpx(xv[0][2], cv[0][2], xv[1][2], cv[1][2]);
            uint2 q11 = packpx(xv[0][3], cv[0][3], xv[1][3], cv[1][3]);
            long o0 = (long)b * pl + (long)fh * W2 + fw;
            *reinterpret_cast<uint4*>(Dpk + o0)      = make_uint4(q00.x, q00.y, q01.x, q01.y);
            *reinterpret_cast<uint4*>(Dpk + o0 + W2) = make_uint4(q10.x, q10.y, q11.x, q11.y);
            float cm0 = cv[0][0], xs0 = xv[0][0];
            if (cv[0][1] > cm0) { cm0 = cv[0][1]; xs0 = xv[0][1]; }
            if (cv[0][2] > cm0) { cm0 = cv[0][2]; xs0 = xv[0][2]; }
            if (cv[0][3] > cm0) { cm0 = cv[0][3]; xs0 = xv[0][3]; }
            float cm1 = cv[1][0], xs1 = xv[1][0];
            if (cv[1][1] > cm1) { cm1 = cv[1][1]; xs1 = xv[1][1]; }
            if (cv[1][2] > cm1) { cm1 = cv[1][2]; xs1 = xv[1][2]; }
            if (cv[1][3] > cm1) { cm1 = cv[1][3]; xs1 = xv[1][3]; }
            int ph = (base_h >> 1) + pr, pw = (base_w >> 1) + pc;
            P2pk[(long)b * (H3 * W3) + (long)ph * W3 + pw] =
                packpx(xs0, cm0 * 0.25f, xs1, cm1 * 0.25f);
        }
    }
}

// ---------------------------------------------------------------------------
// Fused L3: P2pk -> conv w2 -> Gpk (full) + pooled P3pk. Deinterleaved LDS.
// ---------------------------------------------------------------------------
__global__ __launch_bounds__(256) void fused_l3(
    const uint2* __restrict__ P2pk, const float* __restrict__ wb,
    const float* __restrict__ b2,
    uint2* __restrict__ Gpk, uint2* __restrict__ P3pk) {

    __shared__ float4 T0buf[2 * 36 * 19];
    float4* T0e = T0buf; float4* T0o = T0buf + 36 * 19;

    const int tid = threadIdx.x;
    const int base_h = blockIdx.y * 32;
    const int base_w = blockIdx.x * 32;
    const int b = blockIdx.z;
    const long pl = (long)H3 * W3;
    const uint2* ip = P2pk + (long)b * pl;

    for (int i = tid; i < 36 * 18; i += 256) {
        int r = i / 18, cp2 = i % 18;
        int gh = base_h - 2 + r, gw = base_w - 2 + 2 * cp2;
        uint4 pp = make_uint4(0, 0, 0, 0);
        if (gh >= 0 && gh < H3 && gw >= 0 && gw < W3)
            pp = *reinterpret_cast<const uint4*>(ip + (long)gh * W3 + gw);
        T0e[r * 19 + cp2] = unpk(make_uint2(pp.x, pp.y));
        T0o[r * 19 + cp2] = unpk(make_uint2(pp.z, pp.w));
    }
    __syncthreads();

    {
        const float is0 = wb[810], is1 = wb[811];
        const float bb0 = b2[0], bb1 = b2[1];
        const int pr = tid >> 4, pc = tid & 15;
        const int r0 = 2 * pr;
        float acc[2][2][4];
        #pragma unroll
        for (int a = 0; a < 2; ++a)
            #pragma unroll
            for (int o = 0; o < 2; ++o)
                #pragma unroll
                for (int k = 0; k < 4; ++k) acc[a][o][k] = 0.f;
        #pragma unroll
        for (int tr = 0; tr < 6; ++tr) {
            const int rr = (r0 + tr) * 19;
            float4 t[6];
            t[0] = T0e[rr + pc];     t[1] = T0o[rr + pc];
            t[2] = T0e[rr + pc + 1]; t[3] = T0o[rr + pc + 1];
            t[4] = T0e[rr + pc + 2]; t[5] = T0o[rr + pc + 2];
            #pragma unroll
            for (int orr = 0; orr < 2; ++orr) {
                const int dh = tr - orr;
                if (dh < 0 || dh > 4) continue;
                #pragma unroll
                for (int dw = 0; dw < 5; ++dw) {
                    const int k = dh * 5 + dw;
                    float wa0 = wb[96 + k],  wc0 = wb[121 + k];
                    float wa1 = wb[146 + k], wc1 = wb[171 + k];
                    #pragma unroll
                    for (int oc = 0; oc < 2; ++oc) {
                        float4 v = t[dw + oc];
                        acc[orr][oc][0] = fmaf(wa0, v.x, fmaf(wc0, v.z, acc[orr][oc][0]));
                        acc[orr][oc][1] = fmaf(wa0, v.y, fmaf(wc0, v.w, acc[orr][oc][1]));
                        acc[orr][oc][2] = fmaf(wa1, v.x, fmaf(wc1, v.z, acc[orr][oc][2]));
                        acc[orr][oc][3] = fmaf(wa1, v.y, fmaf(wc1, v.w, acc[orr][oc][3]));
                    }
                }
            }
        }
        int fh = base_h + r0, fw = base_w + 2 * pc;
        if (fh < H3 && fw < W3) {
            float xv[2][4], cv[2][4];
            #pragma unroll
            for (int orr = 0; orr < 2; ++orr)
                #pragma unroll
                for (int oc = 0; oc < 2; ++oc) {
                    int q = orr * 2 + oc;
                    float n0 = acc[orr][oc][0], d0 = acc[orr][oc][1];
                    float n1 = acc[orr][oc][2], d1 = acc[orr][oc][3];
                    xv[0][q] = n0 * rcpf_(d0 + EPSF) + bb0;
                    xv[1][q] = n1 * rcpf_(d1 + EPSF) + bb1;
                    cv[0][q] = d0 * is0;
                    cv[1][q] = d1 * is1;
                }
            uint2 q00 = packpx(xv[0][0], cv[0][0], xv[1][0], cv[1][0]);
            uint2 q01 = packpx(xv[0][1], cv[0][1], xv[1][1], cv[1][1]);
            uint2 q10 = packpx(xv[0][2], cv[0][2], xv[1][2], cv[1][2]);
            uint2 q11 = packpx(xv[0][3], cv[0][3], xv[1][3], cv[1][3]);
            long o0 = (long)b * pl + (long)fh * W3 + fw;
            *reinterpret_cast<uint4*>(Gpk + o0)      = make_uint4(q00.x, q00.y, q01.x, q01.y);
            *reinterpret_cast<uint4*>(Gpk + o0 + W3) = make_uint4(q10.x, q10.y, q11.x, q11.y);
            float cm0 = cv[0][0], xs0 = xv[0][0];
            if (cv[0][1] > cm0) { cm0 = cv[0][1]; xs0 = xv[0][1]; }
            if (cv[0][2] > cm0) { cm0 = cv[0][2]; xs0 = xv[0][2]; }
            if (cv[0][3] > cm0) { cm0 = cv[0][3]; xs0 = xv[0][3]; }
            float cm1 = cv[1][0], xs1 = xv[1][0];
            if (cv[1][1] > cm1) { cm1 = cv[1][1]; xs1 = xv[1][1]; }
            if (cv[1][2] > cm1) { cm1 = cv[1][2]; xs1 = xv[1][2]; }
            if (cv[1][3] > cm1) { cm1 = cv[1][3]; xs1 = xv[1][3]; }
            int ph = (base_h >> 1) + pr, pw = (base_w >> 1) + pc;
            P3pk[(long)b * (H4 * W4) + (long)ph * W4 + pw] =
                packpx(xs0, cm0 * 0.25f, xs1, cm1 * 0.25f);
        }
    }
}

// ---------------------------------------------------------------------------
// L4 conv: 5x5 pad2 nconv on packed pixels (w2, b2). Per-pixel (small level).
// ---------------------------------------------------------------------------
__global__ void nconv5_pk(const uint2* __restrict__ in, const float* __restrict__ wb,
                          const float* __restrict__ bias, uint2* __restrict__ out,
                          int H, int W) {
    int idx = blockIdx.x * blockDim.x + threadIdx.x;
    int total = B_ * H * W;
    if (idx >= total) return;
    int w = idx % W; int t = idx / W; int h = t % H; int b = t / H;
    const uint2* ip = in + (long)b * H * W;
    float n0 = 0, d0 = 0, n1 = 0, d1 = 0;
    #pragma unroll
    for (int dh = 0; dh < 5; ++dh) {
        int ih = h + dh - 2;
        if (ih < 0 || ih >= H) continue;
        #pragma unroll
        for (int dw = 0; dw < 5; ++dw) {
            int iw = w + dw - 2;
            if (iw < 0 || iw >= W) continue;
            float4 v = unpk(ip[(long)ih * W + iw]);
            const int k = dh * 5 + dw;
            float wa0 = wb[96 + k],  wc0 = wb[121 + k];
            float wa1 = wb[146 + k], wc1 = wb[171 + k];
            n0 = fmaf(wa0, v.x, fmaf(wc0, v.z, n0));
            d0 = fmaf(wa0, v.y, fmaf(wc0, v.w, d0));
            n1 = fmaf(wa1, v.x, fmaf(wc1, v.z, n1));
            d1 = fmaf(wa1, v.y, fmaf(wc1, v.w, d1));
        }
    }
    out[(long)b * H * W + (long)h * W + w] =
        packpx(n0 * rcpf_(d0 + EPSF) + bias[0], d0 * wb[810],
               n1 * rcpf_(d1 + EPSF) + bias[1], d1 * wb[811]);
}

// ---------------------------------------------------------------------------
// Decoder H3: F = nconv(cat(G, up2(I)), w4, b4). Per-pixel packed.
// ---------------------------------------------------------------------------
__global__ void nconv_cat_pk(const uint2* __restrict__ nat, const uint2* __restrict__ up,
                             const float* __restrict__ wb, const float* __restrict__ bias,
                             uint2* __restrict__ out, int H, int W) {
    int idx = blockIdx.x * blockDim.x + threadIdx.x;
    int total = B_ * H * W;
    if (idx >= total) return;
    int Hh = H / 2, Wh = W / 2;
    int w = idx % W; int t = idx / W; int h = t % H; int b = t / H;
    const uint2* np = nat + (long)b * H * W;
    const uint2* upp = up + (long)b * Hh * Wh;
    float n0 = 0, d0 = 0, n1 = 0, d1 = 0;
    #pragma unroll
    for (int dh = 0; dh < 3; ++dh) {
        int ih = h + dh - 1;
        if (ih < 0 || ih >= H) continue;
        #pragma unroll
        for (int dw = 0; dw < 3; ++dw) {
            int iw = w + dw - 1;
            if (iw < 0 || iw >= W) continue;
            float4 aN = unpk(np[(long)ih * W + iw]);
            float4 eU = unpk(upp[(long)(ih >> 1) * Wh + (iw >> 1)]);
            const int k = dh * 3 + dw;
            float na0 = wb[416 + k], nb0 = wb[425 + k], ua0 = wb[434 + k], ub0 = wb[443 + k];
            float na1 = wb[452 + k], nb1 = wb[461 + k], ua1 = wb[470 + k], ub1 = wb[479 + k];
            n0 = fmaf(na0, aN.x, fmaf(nb0, aN.z, fmaf(ua0, eU.x, fmaf(ub0, eU.z, n0))));
            d0 = fmaf(na0, aN.y, fmaf(nb0, aN.w, fmaf(ua0, eU.y, fmaf(ub0, eU.w, d0))));
            n1 = fmaf(na1, aN.x, fmaf(nb1, aN.z, fmaf(ua1, eU.x, fmaf(ub1, eU.z, n1))));
            d1 = fmaf(na1, aN.y, fmaf(nb1, aN.w, fmaf(ua1, eU.y, fmaf(ub1, eU.w, d1))));
        }
    }
    out[(long)b * H * W + (long)h * W + w] =
        packpx(n0 * rcpf_(d0 + EPSF) + bias[0], d0 * wb[814],
               n1 * rcpf_(d1 + EPSF) + bias[1], d1 * wb[815]);
}

// ---------------------------------------------------------------------------
// Decoder H2 tiled (round-5 proven): register windows a4/e3.
// ---------------------------------------------------------------------------
__global__ __launch_bounds__(256) void nconv_cat_h2t(
    const uint2* __restrict__ Dpk, const uint2* __restrict__ Fpk,
    const float* __restrict__ wb, const float* __restrict__ b5,
    uint2* __restrict__ Epk) {

    __shared__ float4 aTbuf[2 * 34 * 17];
    __shared__ float4 eT[18 * 19];
    float4* aTe = aTbuf; float4* aTo = aTbuf + 34 * 17;

    const int tid = threadIdx.x;
    const int bh = blockIdx.y * 32, bw = blockIdx.x * 32, b = blockIdx.z;
    const int eh0 = (bh - 1) >> 1, ew0 = (bw - 1) >> 1;
    const uint2* dp = Dpk + (long)b * (H2 * W2);
    const uint2* fp = Fpk + (long)b * (H3 * W3);

    for (int i = tid; i < 34 * 17; i += 256) {
        int r = i / 17, cp2 = i % 17;
        int gh = bh - 1 + r;
        int gw0 = bw - 1 + 2 * cp2, gw1 = gw0 + 1;
        uint2 p0 = make_uint2(0, 0), p1 = make_uint2(0, 0);
        if (gh >= 0 && gh < H2) {
            if (gw0 >= 0 && gw0 < W2) p0 = dp[(long)gh * W2 + gw0];
            if (gw1 < W2)             p1 = dp[(long)gh * W2 + gw1];
        }
        aTe[r * 17 + cp2] = unpk(p0);
        aTo[r * 17 + cp2] = unpk(p1);
    }
    for (int i = tid; i < 18 * 18; i += 256) {
        int r = i / 18, c = i % 18;
        int gh = eh0 + r, gw = ew0 + c;
        float4 v = make_float4(0.f, 0.f, 0.f, 0.f);
        if (gh >= 0 && gh < H3 && gw >= 0 && gw < W3)
            v = unpk(fp[(long)gh * W3 + gw]);
        eT[r * 19 + c] = v;
    }
    __syncthreads();

    const int pr = tid >> 4, pc = tid & 15;
    const int r0 = 2 * pr;
    float4 a4[4][4], e3[3][3];
    #pragma unroll
    for (int j = 0; j < 4; ++j) {
        const int rr = (r0 + j) * 17;
        a4[j][0] = aTe[rr + pc];     a4[j][1] = aTo[rr + pc];
        a4[j][2] = aTe[rr + pc + 1]; a4[j][3] = aTo[rr + pc + 1];
    }
    #pragma unroll
    for (int j = 0; j < 3; ++j)
        #pragma unroll
        for (int k = 0; k < 3; ++k) e3[j][k] = eT[(pr + j) * 19 + pc + k];

    float acc[2][2][4];
    #pragma unroll
    for (int a = 0; a < 2; ++a)
        #pragma unroll
        for (int o = 0; o < 2; ++o)
            #pragma unroll
            for (int k = 0; k < 4; ++k) acc[a][o][k] = 0.f;

    #pragma unroll
    for (int orr = 0; orr < 2; ++orr)
        #pragma unroll
        for (int dh = 0; dh < 3; ++dh)
            #pragma unroll
            for (int oc = 0; oc < 2; ++oc)
                #pragma unroll
                for (int dw = 0; dw < 3; ++dw) {
                    float4 aN = a4[orr + dh][oc + dw];
                    float4 eU = e3[(orr + dh + 1) >> 1][(oc + dw + 1) >> 1];
                    const int k = dh * 3 + dw;
                    float na0 = wb[544 + k], nb0 = wb[553 + k], ua0 = wb[562 + k], ub0 = wb[571 + k];
                    float na1 = wb[580 + k], nb1 = wb[589 + k], ua1 = wb[598 + k], ub1 = wb[607 + k];
                    acc[orr][oc][0] = fmaf(na0, aN.x, fmaf(nb0, aN.z, fmaf(ua0, eU.x, fmaf(ub0, eU.z, acc[orr][oc][0]))));
                    acc[orr][oc][1] = fmaf(na0, aN.y, fmaf(nb0, aN.w, fmaf(ua0, eU.y, fmaf(ub0, eU.w, acc[orr][oc][1]))));
                    acc[orr][oc][2] = fmaf(na1, aN.x, fmaf(nb1, aN.z, fmaf(ua1, eU.x, fmaf(ub1, eU.z, acc[orr][oc][2]))));
                    acc[orr][oc][3] = fmaf(na1, aN.y, fmaf(nb1, aN.w, fmaf(ua1, eU.y, fmaf(ub1, eU.w, acc[orr][oc][3]))));
                }

    int fh = bh + r0, fw = bw + 2 * pc;
    if (fh < H2) {
        const float is0 = wb[816], is1 = wb[817];
        const float bb0 = b5[0], bb1 = b5[1];
        float xv[2][4], cv[2][4];
        #pragma unroll
        for (int orr = 0; orr < 2; ++orr)
            #pragma unroll
            for (int oc = 0; oc < 2; ++oc) {
                int q = orr * 2 + oc;
                float n0 = acc[orr][oc][0], d0 = acc[orr][oc][1];
                float n1 = acc[orr][oc][2], d1 = acc[orr][oc][3];
                xv[0][q] = n0 * rcpf_(d0 + EPSF) + bb0;
                xv[1][q] = n1 * rcpf_(d1 + EPSF) + bb1;
                cv[0][q] = d0 * is0;
                cv[1][q] = d1 * is1;
            }
        uint2 q00 = packpx(xv[0][0], cv[0][0], xv[1][0], cv[1][0]);
        uint2 q01 = packpx(xv[0][1], cv[0][1], xv[1][1], cv[1][1]);
        uint2 q10 = packpx(xv[0][2], cv[0][2], xv[1][2], cv[1][2]);
        uint2 q11 = packpx(xv[0][3], cv[0][3], xv[1][3], cv[1][3]);
        long o0 = (long)b * (H2 * W2) + (long)fh * W2 + fw;
        *reinterpret_cast<uint4*>(Epk + o0)      = make_uint4(q00.x, q00.y, q01.x, q01.y);
        *reinterpret_cast<uint4*>(Epk + o0 + W2) = make_uint4(q10.x, q10.y, q11.x, q11.y);
    }
}

// ---------------------------------------------------------------------------
// Final (round-5 proven): register windows a4/e3; w6 3x3 + w7 1x1 -> f32.
// ---------------------------------------------------------------------------
__global__ __launch_bounds__(256) void final_tiled(
    const uint2* __restrict__ Apk, const uint2* __restrict__ Epk,
    const float* __restrict__ wb,
    const float* __restrict__ b6g, const float* __restrict__ b7g,
    float* __restrict__ oX, float* __restrict__ oC) {

    __shared__ float4 aTbuf[2 * 34 * 17];
    __shared__ float4 eT[18 * 19];
    float4* aTe = aTbuf; float4* aTo = aTbuf + 34 * 17;

    const int tid = threadIdx.x;
    const int bh = blockIdx.y * 32, bw = blockIdx.x * 32, b = blockIdx.z;
    const int eh0 = (bh - 1) >> 1, ew0 = (bw - 1) >> 1;
    const uint2* ap = Apk + (long)b * (H1 * W1);
    const uint2* ep = Epk + (long)b * (H2 * W2);

    for (int i = tid; i < 34 * 17; i += 256) {
        int r = i / 17, cp2 = i % 17;
        int gh = bh - 1 + r;
        int gw0 = bw - 1 + 2 * cp2, gw1 = gw0 + 1;
        uint2 p0 = make_uint2(0, 0), p1 = make_uint2(0, 0);
        if (gh >= 0 && gh < H1) {
            if (gw0 >= 0 && gw0 < W1) p0 = ap[(long)gh * W1 + gw0];
            if (gw1 < W1)             p1 = ap[(long)gh * W1 + gw1];
        }
        aTe[r * 17 + cp2] = unpk(p0);
        aTo[r * 17 + cp2] = unpk(p1);
    }
    for (int i = tid; i < 18 * 18; i += 256) {
        int r = i / 18, c = i % 18;
        int gh = eh0 + r, gw = ew0 + c;
        float4 v = make_float4(0.f, 0.f, 0.f, 0.f);
        if (gh >= 0 && gh < H2 && gw >= 0 && gw < W2)
            v = unpk(ep[(long)gh * W2 + gw]);
        eT[r * 19 + c] = v;
    }
    __syncthreads();

    const int pr = tid >> 4, pc = tid & 15;
    const int r0 = 2 * pr;
    float4 a4[4][4], e3[3][3];
    #pragma unroll
    for (int j = 0; j < 4; ++j) {
        const int rr = (r0 + j) * 17;
        a4[j][0] = aTe[rr + pc];     a4[j][1] = aTo[rr + pc];
        a4[j][2] = aTe[rr + pc + 1]; a4[j][3] = aTo[rr + pc + 1];
    }
    #pragma unroll
    for (int j = 0; j < 3; ++j)
        #pragma unroll
        for (int k = 0; k < 3; ++k) e3[j][k] = eT[(pr + j) * 19 + pc + k];

    float acc[2][2][4];
    #pragma unroll
    for (int a = 0; a < 2; ++a)
        #pragma unroll
        for (int o = 0; o < 2; ++o)
            #pragma unroll
            for (int k = 0; k < 4; ++k) acc[a][o][k] = 0.f;

    // w6 layout: up (E) = ci 0-1, native (A) = ci 2-3.
    #pragma unroll
    for (int orr = 0; orr < 2; ++orr)
        #pragma unroll
        for (int dh = 0; dh < 3; ++dh)
            #pragma unroll
            for (int oc = 0; oc < 2; ++oc)
                #pragma unroll
                for (int dw = 0; dw < 3; ++dw) {
                    float4 aN = a4[orr + dh][oc + dw];
                    float4 eU = e3[(orr + dh + 1) >> 1][(oc + dw + 1) >> 1];
                    const int k = dh * 3 + dw;
                    float ua0 = wb[672 + k], ub0 = wb[681 + k], na0 = wb[690 + k], nb0 = wb[699 + k];
                    float ua1 = wb[708 + k], ub1 = wb[717 + k], na1 = wb[726 + k], nb1 = wb[735 + k];
                    acc[orr][oc][0] = fmaf(ua0, eU.x, fmaf(ub0, eU.z, fmaf(na0, aN.x, fmaf(nb0, aN.z, acc[orr][oc][0]))));
                    acc[orr][oc][1] = fmaf(ua0, eU.y, fmaf(ub0, eU.w, fmaf(na0, aN.y, fmaf(nb0, aN.w, acc[orr][oc][1]))));
                    acc[orr][oc][2] = fmaf(ua1, eU.x, fmaf(ub1, eU.z, fmaf(na1, aN.x, fmaf(nb1, aN.z, acc[orr][oc][2]))));
                    acc[orr][oc][3] = fmaf(ua1, eU.y, fmaf(ub1, eU.w, fmaf(na1, aN.y, fmaf(nb1, aN.w, acc[orr][oc][3]))));
                }

    const float is60 = wb[818], is61 = wb[819];
    const float bb60 = b6g[0], bb61 = b6g[1];
    const float w70 = wb[800], w71 = wb[801];
    const float is7 = wb[820], bb7 = b7g[0];
    float ox[2][2], ocv[2][2];
    #pragma unroll
    for (int orr = 0; orr < 2; ++orr)
        #pragma unroll
        for (int oc = 0; oc < 2; ++oc) {
            float n0 = acc[orr][oc][0], d0 = acc[orr][oc][1];
            float n1 = acc[orr][oc][2], d1 = acc[orr][oc][3];
            float x0v = n0 * rcpf_(d0 + EPSF) + bb60;
            float x1v = n1 * rcpf_(d1 + EPSF) + bb61;
            float c0v = d0 * is60, c1v = d1 * is61;
            float den7 = fmaf(w70, c0v, w71 * c1v);
            float nom7 = fmaf(w70, x0v * c0v, w71 * (x1v * c1v));
            ox[orr][oc] = nom7 * rcpf_(den7 + EPSF) + bb7;
            ocv[orr][oc] = den7 * is7;
        }
    long o = (long)b * (H1 * W1) + (long)(bh + r0) * W1 + (bw + 2 * pc);
    *reinterpret_cast<float2*>(oX + o)      = make_float2(ox[0][0], ox[0][1]);
    *reinterpret_cast<float2*>(oX + o + W1) = make_float2(ox[1][0], ox[1][1]);
    *reinterpret_cast<float2*>(oC + o)      = make_float2(ocv[0][0], ocv[0][1]);
    *reinterpret_cast<float2*>(oC + o + W1) = make_float2(ocv[1][0], ocv[1][1]);
}

extern "C" void kernel_launch(void* const* d_in, const int* in_sizes, int n_in,
                              void* d_out, int out_size, void* d_ws, size_t ws_size,
                              hipStream_t stream) {
    const float* x0 = (const float*)d_in[0];
    const float* c0 = (const float*)d_in[1];
    const float* w1 = (const float*)d_in[2];
    const float* b1 = (const float*)d_in[3];
    const float* w2 = (const float*)d_in[4];
    const float* b2 = (const float*)d_in[5];
    const float* w3 = (const float*)d_in[6];
    const float* b3 = (const float*)d_in[7];
    const float* w4 = (const float*)d_in[8];
    const float* b4 = (const float*)d_in[9];
    const float* w5 = (const float*)d_in[10];
    const float* b5 = (const float*)d_in[11];
    const float* w6 = (const float*)d_in[12];
    const float* b6 = (const float*)d_in[13];
    const float* w7 = (const float*)d_in[14];
    const float* b7 = (const float*)d_in[15];

    const long N1 = (long)B_ * H1 * W1;     // 6,848,512 pixels (full res)
    const long N2 = N1 / 4, N3 = N1 / 16, N4 = N1 / 64;

    // ws: [wb 4KB][Apk 8*N1][Epk 8*N2] ~ 68.5 MB
    float* wb = (float*)d_ws;
    uint2* Apk = (uint2*)((char*)d_ws + 4096);
    uint2* Epk = Apk + N1;

    // d_out (N1 uint2 capacity) as packed scratch; final pass reads only ws.
    uint2* R = (uint2*)d_out;
    uint2* P1pk = R;                 // N2
    uint2* Dpk  = R + N2;            // N2
    uint2* P2pk = R + 2 * N2;        // N3
    uint2* Gpk  = P2pk + N3;         // N3
    uint2* P3pk = Gpk + N3;          // N4
    uint2* Ipk  = P3pk + N4;         // N4
    uint2* Fpk  = Ipk + N4;          // N3

    float* oX = (float*)d_out;
    float* oC = oX + N1;

    prep_weights<<<1, 256, 0, stream>>>(w1, w2, w3, w4, w5, w6, w7, wb);

    dim3 gridF(W1 / TDIM, H1 / TDIM, B_);           // 38 x 11 x 16
    fused_l1pool<<<gridF, 256, 0, stream>>>(x0, c0, wb, b1, b2, b3, Apk, P1pk);

    dim3 gridL2(W2 / 32, (H2 + 31) / 32, B_);       // 19 x 6 x 16
    fused_l2<<<gridL2, 256, 0, stream>>>(P1pk, wb, b2, b3, Dpk, P2pk);

    dim3 gridL3((W3 + 31) / 32, (H3 + 31) / 32, B_); // 10 x 3 x 16
    fused_l3<<<gridL3, 256, 0, stream>>>(P2pk, wb, b2, Gpk, P3pk);

    const int g4 = (B_ * H4 * W4 + 255) / 256;
    nconv5_pk<<<g4, 256, 0, stream>>>(P3pk, wb, b2, Ipk, H4, W4);   // I = x4,c4

    const int g3 = (B_ * H3 * W3 + 255) / 256;
    nconv_cat_pk<<<g3, 256, 0, stream>>>(Gpk, Ipk, wb, b4, Fpk, H3, W3);  // F = x34

    nconv_cat_h2t<<<gridL2, 256, 0, stream>>>(Dpk, Fpk, wb, b5, Epk);     // E = x23 (ws)

    dim3 gridL(W1 / 32, H1 / 32, B_);               // 38 x 11 x 16
    final_tiled<<<gridL, 256, 0, stream>>>(Apk, Epk, wb, b6, b7, oX, oC);
}